// Round 19
// baseline (873.420 us; speedup 1.0000x reference)
//
#include <hip/hip_runtime.h>

constexpr int NN = 150000;   // nodes
constexpr int NE = 4800000;  // edges
constexpr int NG = 512;      // graphs
constexpr int H  = 16;       // hidden
constexpr int NB   = 512;    // coarse dst-buckets
constexpr int NPBK = 293;    // nodes per bucket (512*293 = 150016 >= NN)
constexpr int NBLK = 512;    // streaming blocks for hist/part
constexpr int CHUNK = NE / NBLK;   // 9375 edges per block (exact)

__device__ inline unsigned short f2bf(float f) {
    union { float f; unsigned u; } v; v.f = f;
    unsigned r = v.u + 0x7FFFu + ((v.u >> 16) & 1u);   // RNE
    return (unsigned short)(r >> 16);
}
__device__ inline float bf2f(unsigned short s) {
    union { unsigned u; float f; } v; v.u = ((unsigned)s) << 16;
    return v.f;
}

// ---------- phase A: per-block LDS histogram -> mat[b][bucket] ----------
__global__ void k_hist2(const int* __restrict__ dst, int* __restrict__ mat) {
    __shared__ int cnt[NB];
    cnt[threadIdx.x] = 0;
    __syncthreads();
    int b = blockIdx.x;
    int e0 = b * CHUNK, e1 = e0 + CHUNK;
    for (int e = e0 + (int)threadIdx.x; e < e1; e += 512)
        atomicAdd(&cnt[dst[e] / NPBK], 1);
    __syncthreads();
    mat[b * NB + threadIdx.x] = cnt[threadIdx.x];
}

// ---------- column scan: mat[:,j] -> exclusive prefix (in place), totals ----------
__global__ void k_scanb(int* __restrict__ mat, int* __restrict__ tot) {
    __shared__ int tmp[NBLK];
    int j = blockIdx.x, t = threadIdx.x;
    int v = mat[t * NB + j];
    tmp[t] = v;
    __syncthreads();
    for (int off = 1; off < NBLK; off <<= 1) {
        int a = (t >= off) ? tmp[t - off] : 0;
        __syncthreads();
        tmp[t] += a;
        __syncthreads();
    }
    mat[t * NB + j] = tmp[t] - v;               // exclusive within column
    if (t == NBLK - 1) tot[j] = tmp[t];
}

// ---------- bucket base scan (exclusive over NB buckets) ----------
__global__ void k_scant(const int* __restrict__ tot, int* __restrict__ base) {
    __shared__ int tmp[NB];
    int t = threadIdx.x;
    int v = tot[t];
    tmp[t] = v;
    __syncthreads();
    for (int off = 1; off < NB; off <<= 1) {
        int a = (t >= off) ? tmp[t - off] : 0;
        __syncthreads();
        tmp[t] += a;
        __syncthreads();
    }
    base[t] = tmp[t] - v;
    if (t == 0) base[NB] = NE;
}

// ---------- phase B: LDS-staged partition (counts from mat), coalesced writeout ----------
__global__ void k_part2(const int* __restrict__ src, const int* __restrict__ dst,
                        const int* __restrict__ mat, const int* __restrict__ tot,
                        const int* __restrict__ base, unsigned* __restrict__ ed) {
    __shared__ int off[NB];          // exclusive local offsets
    __shared__ int gsnap[NB];        // global run base per bucket
    __shared__ int lcur[NB];         // local scatter cursors
    __shared__ unsigned stg[CHUNK];  // 37.5 KB staging
    int b = blockIdx.x, t = threadIdx.x;
    int e0 = b * CHUNK, e1 = e0 + CHUNK;
    int exg = mat[b * NB + t];                       // col-exclusive (blocks < b)
    int nxt = (b + 1 < NBLK) ? mat[(b + 1) * NB + t] : tot[t];
    int v = nxt - exg;                               // my count for bucket t
    gsnap[t] = base[t] + exg;
    off[t] = v;
    __syncthreads();
    for (int o = 1; o < NB; o <<= 1) {
        int a = (t >= o) ? off[t - o] : 0;
        __syncthreads();
        off[t] += a;
        __syncthreads();
    }
    int excl = off[t] - v;
    __syncthreads();
    off[t]  = excl;
    lcur[t] = excl;
    __syncthreads();
    // scatter into LDS staging (bucket-grouped)
    for (int e = e0 + t; e < e1; e += 512) {
        int d = dst[e];
        int bq = d / NPBK;
        int p = atomicAdd(&lcur[bq], 1);
        stg[p] = (unsigned)src[e] | ((unsigned)(d - bq * NPBK) << 18);
    }
    __syncthreads();
    // writeout: one wave per bucket run, coalesced
    int wave = t >> 6, lane = t & 63;
    for (int bb = wave; bb < NB; bb += 8) {
        int o = off[bb];
        int c = lcur[bb] - o;
        int gb = gsnap[bb];
        for (int k = lane; k < c; k += 64)
            ed[gb + k] = stg[o + k];
    }
}

// ---------- per-bucket degree count -> disq ----------
__global__ void k_disq_b(const unsigned* __restrict__ ed, const int* __restrict__ base,
                         float* __restrict__ disq) {
    __shared__ int cnt[NPBK];
    int j = blockIdx.x, t = threadIdx.x;
    for (int q = t; q < NPBK; q += 512) cnt[q] = 0;
    __syncthreads();
    int e0 = base[j], e1 = base[j + 1];
    for (int e = e0 + t; e < e1; e += 512)
        atomicAdd(&cnt[ed[e] >> 18], 1);
    __syncthreads();
    int n0 = j * NPBK;
    for (int q = t; q < NPBK; q += 512) {
        int n = n0 + q;
        if (n < NN) disq[n] = rsqrtf((float)(cnt[q] + 1));   // +1 self-loop
    }
}

// ---------- y = (x @ W1) * disq  -> bf16 ----------
__global__ void k_xw1(const float* __restrict__ x, const float* __restrict__ W1,
                      const float* __restrict__ disq, unsigned short* __restrict__ y) {
    __shared__ float w[4 * H];
    if (threadIdx.x < 4 * H) w[threadIdx.x] = W1[threadIdx.x];
    __syncthreads();
    int i = blockIdx.x * blockDim.x + threadIdx.x;
    if (i >= NN) return;
    float4 xv = ((const float4*)x)[i];
    float d = disq[i];
    float o[H];
#pragma unroll
    for (int h = 0; h < H; ++h)
        o[h] = (xv.x * w[0*H + h] + xv.y * w[1*H + h] +
                xv.z * w[2*H + h] + xv.w * w[3*H + h]) * d;
    unsigned pk[8];
#pragma unroll
    for (int q = 0; q < 8; ++q)
        pk[q] = (unsigned)f2bf(o[2*q]) | ((unsigned)f2bf(o[2*q+1]) << 16);
    uint4* yp = (uint4*)(y + (size_t)i * H);
    yp[0] = make_uint4(pk[0], pk[1], pk[2], pk[3]);
    yp[1] = make_uint4(pk[4], pk[5], pk[6], pk[7]);
}

// ---------- fused conv: per-bucket LDS accumulate from ed, 8-wide unroll ----------
// h[n] = relu(disq[n] * (y[n] + sum_{e:dst=n} y[src_e]) + b)
__global__ void k_conv8(const unsigned* __restrict__ ed, const int* __restrict__ base,
                        const unsigned short* __restrict__ y, const float* __restrict__ disq,
                        const float* __restrict__ bias, float* __restrict__ hout) {
    __shared__ float acc[NPBK * H];     // 18.3 KB
    __shared__ float bs[H];
    int j = blockIdx.x, t = threadIdx.x;
    if (t < H) bs[t] = bias[t];
    for (int q = t; q < NPBK * H; q += 512) acc[q] = 0.f;
    __syncthreads();
    int e0 = base[j], e1 = base[j + 1];
    int m = e1 - e0;
    int lane = t & 15, grp = t >> 4;      // 32 groups of 16 lanes
    int nfull = (m / 256) * 256;          // 8 edges x 32 groups per round
    for (int eb = e0 + grp * 8; eb < e0 + nfull; eb += 256) {
        unsigned w0 = ed[eb+0], w1 = ed[eb+1], w2 = ed[eb+2], w3 = ed[eb+3];
        unsigned w4 = ed[eb+4], w5 = ed[eb+5], w6 = ed[eb+6], w7 = ed[eb+7];
        float v0 = bf2f(y[(size_t)(w0 & 0x3FFFFu) * H + lane]);
        float v1 = bf2f(y[(size_t)(w1 & 0x3FFFFu) * H + lane]);
        float v2 = bf2f(y[(size_t)(w2 & 0x3FFFFu) * H + lane]);
        float v3 = bf2f(y[(size_t)(w3 & 0x3FFFFu) * H + lane]);
        float v4 = bf2f(y[(size_t)(w4 & 0x3FFFFu) * H + lane]);
        float v5 = bf2f(y[(size_t)(w5 & 0x3FFFFu) * H + lane]);
        float v6 = bf2f(y[(size_t)(w6 & 0x3FFFFu) * H + lane]);
        float v7 = bf2f(y[(size_t)(w7 & 0x3FFFFu) * H + lane]);
        atomicAdd(&acc[(w0 >> 18) * H + lane], v0);
        atomicAdd(&acc[(w1 >> 18) * H + lane], v1);
        atomicAdd(&acc[(w2 >> 18) * H + lane], v2);
        atomicAdd(&acc[(w3 >> 18) * H + lane], v3);
        atomicAdd(&acc[(w4 >> 18) * H + lane], v4);
        atomicAdd(&acc[(w5 >> 18) * H + lane], v5);
        atomicAdd(&acc[(w6 >> 18) * H + lane], v6);
        atomicAdd(&acc[(w7 >> 18) * H + lane], v7);
    }
    for (int e = e0 + nfull + grp; e < e1; e += 32) {
        unsigned w = ed[e];
        atomicAdd(&acc[(w >> 18) * H + lane], bf2f(y[(size_t)(w & 0x3FFFFu) * H + lane]));
    }
    __syncthreads();
    int n0 = j * NPBK;
    for (int q = grp; q < NPBK; q += 32) {
        int n = n0 + q;
        if (n >= NN) break;
        float a = acc[q * H + lane] + bf2f(y[(size_t)n * H + lane]);   // self-loop
        hout[(size_t)n * H + lane] = fmaxf(fmaf(a, disq[n], bs[lane]), 0.f);
    }
}

// ---------- y = (h @ W2) * disq -> bf16 ----------
__global__ void k_hw2(const float* __restrict__ hin, const float* __restrict__ W2,
                      const float* __restrict__ disq, unsigned short* __restrict__ yout) {
    __shared__ float w[H * H];
    if (threadIdx.x < H * H) w[threadIdx.x] = W2[threadIdx.x];
    __syncthreads();
    int i = blockIdx.x * blockDim.x + threadIdx.x;
    if (i >= NN) return;
    float hv[H];
    const float4* hp = (const float4*)(hin + (size_t)i * H);
#pragma unroll
    for (int q = 0; q < 4; ++q) ((float4*)hv)[q] = hp[q];
    float d = disq[i];
    float o[H];
#pragma unroll
    for (int h = 0; h < H; ++h) {
        float s = 0.f;
#pragma unroll
        for (int k = 0; k < H; ++k) s += hv[k] * w[k*H + h];
        o[h] = s * d;
    }
    unsigned pk[8];
#pragma unroll
    for (int q = 0; q < 8; ++q)
        pk[q] = (unsigned)f2bf(o[2*q]) | ((unsigned)f2bf(o[2*q+1]) << 16);
    uint4* yp = (uint4*)(yout + (size_t)i * H);
    yp[0] = make_uint4(pk[0], pk[1], pk[2], pk[3]);
    yp[1] = make_uint4(pk[4], pk[5], pk[6], pk[7]);
}

// ---------- pool: one block per graph, 16 groups x 16 lanes + LDS tree ----------
__global__ void k_pool_blk(const float* __restrict__ h, const int* __restrict__ batch,
                           float* __restrict__ gout) {
    __shared__ float red[16][H + 1];
    int g    = blockIdx.x;
    int lane = threadIdx.x & 15;
    int grp  = threadIdx.x >> 4;                 // 0..15
    int lo = 0, hi = NN;
    while (lo < hi) { int m = (lo + hi) >> 1; if (batch[m] < g) lo = m + 1; else hi = m; }
    int start = lo;
    hi = NN;
    while (lo < hi) { int m = (lo + hi) >> 1; if (batch[m] < g + 1) lo = m + 1; else hi = m; }
    int end = lo;
    float acc = 0.f;
    for (int i = start + grp; i < end; i += 16)
        acc += h[(size_t)i * H + lane];
    red[grp][lane] = acc;
    __syncthreads();
    if (grp < 8) red[grp][lane] += red[grp + 8][lane];
    __syncthreads();
    if (grp < 4) red[grp][lane] += red[grp + 4][lane];
    __syncthreads();
    if (grp < 2) red[grp][lane] += red[grp + 2][lane];
    __syncthreads();
    if (grp == 0)
        gout[(size_t)g * H + lane] = red[0][lane] + red[1][lane];
}

// ---------- final MLP ----------
__global__ void k_mlp(const float* __restrict__ g, const float* __restrict__ Wf1,
                      const float* __restrict__ bf1, const float* __restrict__ Wf2,
                      const float* __restrict__ bf2, float* __restrict__ out) {
    __shared__ float w1[H * H];
    __shared__ float b1s[H];
    __shared__ float w2[H];
    __shared__ float b2s;
    if (threadIdx.x < H * H) w1[threadIdx.x] = Wf1[threadIdx.x];
    if (threadIdx.x < H) { b1s[threadIdx.x] = bf1[threadIdx.x]; w2[threadIdx.x] = Wf2[threadIdx.x]; }
    if (threadIdx.x == 0) b2s = bf2[0];
    __syncthreads();
    int i = blockIdx.x * blockDim.x + threadIdx.x;
    if (i >= NG) return;
    float gv[H];
    const float4* gp = (const float4*)(g + (size_t)i * H);
#pragma unroll
    for (int q = 0; q < 4; ++q) ((float4*)gv)[q] = gp[q];
    float s2 = 0.f;
#pragma unroll
    for (int h = 0; h < H; ++h) {
        float t = b1s[h];
#pragma unroll
        for (int k = 0; k < H; ++k) t += gv[k] * w1[k*H + h];
        s2 += fmaxf(t, 0.f) * w2[h];
    }
    out[i] = s2 + b2s;
}

// ================= fallback (baseline atomic path, f32) =================
__global__ void k_deg_init(float* __restrict__ deg) {
    int i = blockIdx.x * blockDim.x + threadIdx.x;
    if (i < NN) deg[i] = 1.0f;
}
__global__ void k_deg_edges(const int* __restrict__ dst, float* __restrict__ deg) {
    int i = blockIdx.x * blockDim.x + threadIdx.x;
    if (i < NE) atomicAdd(&deg[dst[i]], 1.0f);
}
__global__ void k_disq(float* __restrict__ deg) {
    int i = blockIdx.x * blockDim.x + threadIdx.x;
    if (i < NN) deg[i] = rsqrtf(deg[i]);
}
__global__ void k_xw1f(const float* __restrict__ x, const float* __restrict__ W1,
                       const float* __restrict__ disq, float* __restrict__ y) {
    __shared__ float w[4 * H];
    if (threadIdx.x < 4 * H) w[threadIdx.x] = W1[threadIdx.x];
    __syncthreads();
    int i = blockIdx.x * blockDim.x + threadIdx.x;
    if (i >= NN) return;
    float4 xv = ((const float4*)x)[i];
    float d = disq[i];
    float o[H];
#pragma unroll
    for (int h = 0; h < H; ++h)
        o[h] = (xv.x * w[0*H + h] + xv.y * w[1*H + h] +
                xv.z * w[2*H + h] + xv.w * w[3*H + h]) * d;
    float4* yp = (float4*)(y + (size_t)i * H);
#pragma unroll
    for (int q = 0; q < 4; ++q) yp[q] = ((float4*)o)[q];
}
__global__ void k_hw2f(const float* __restrict__ hin, const float* __restrict__ W2,
                       const float* __restrict__ disq, float* __restrict__ yout) {
    __shared__ float w[H * H];
    if (threadIdx.x < H * H) w[threadIdx.x] = W2[threadIdx.x];
    __syncthreads();
    int i = blockIdx.x * blockDim.x + threadIdx.x;
    if (i >= NN) return;
    float hv[H];
    const float4* hp = (const float4*)(hin + (size_t)i * H);
#pragma unroll
    for (int q = 0; q < 4; ++q) ((float4*)hv)[q] = hp[q];
    float d = disq[i];
    float o[H];
#pragma unroll
    for (int h = 0; h < H; ++h) {
        float s = 0.f;
#pragma unroll
        for (int k = 0; k < H; ++k) s += hv[k] * w[k*H + h];
        o[h] = s * d;
    }
    float4* yp = (float4*)(yout + (size_t)i * H);
#pragma unroll
    for (int q = 0; q < 4; ++q) yp[q] = ((float4*)o)[q];
}
__global__ void k_scatter(const int* __restrict__ src, const int* __restrict__ dst,
                          const float* __restrict__ y, float* __restrict__ acc) {
    int i = blockIdx.x * blockDim.x + threadIdx.x;
    if (i >= NE) return;
    int s = src[i], d = dst[i];
    const float4* yp = (const float4*)(y + (size_t)s * H);
    float* ap = acc + (size_t)d * H;
#pragma unroll
    for (int q = 0; q < 4; ++q) {
        float4 v = yp[q];
        atomicAdd(ap + q*4 + 0, v.x);
        atomicAdd(ap + q*4 + 1, v.y);
        atomicAdd(ap + q*4 + 2, v.z);
        atomicAdd(ap + q*4 + 3, v.w);
    }
}
__global__ void k_post(const float* __restrict__ acc, const float* __restrict__ disq,
                       const float* __restrict__ b, float* __restrict__ hout) {
    __shared__ float bs[H];
    if (threadIdx.x < H) bs[threadIdx.x] = b[threadIdx.x];
    __syncthreads();
    int i = blockIdx.x * blockDim.x + threadIdx.x;
    if (i >= NN) return;
    float d = disq[i];
    const float4* ap = (const float4*)(acc + (size_t)i * H);
    float4* hp = (float4*)(hout + (size_t)i * H);
#pragma unroll
    for (int q = 0; q < 4; ++q) {
        float4 v = ap[q];
        float4 r;
        r.x = fmaxf(v.x * d + bs[q*4+0], 0.f);
        r.y = fmaxf(v.y * d + bs[q*4+1], 0.f);
        r.z = fmaxf(v.z * d + bs[q*4+2], 0.f);
        r.w = fmaxf(v.w * d + bs[q*4+3], 0.f);
        hp[q] = r;
    }
}

extern "C" void kernel_launch(void* const* d_in, const int* in_sizes, int n_in,
                              void* d_out, int out_size, void* d_ws, size_t ws_size,
                              hipStream_t stream) {
    const float* x   = (const float*)d_in[0];
    const float* W1  = (const float*)d_in[1];
    const float* b1  = (const float*)d_in[2];
    const float* W2  = (const float*)d_in[3];
    const float* b2  = (const float*)d_in[4];
    const float* Wf1 = (const float*)d_in[5];
    const float* bf1 = (const float*)d_in[6];
    const float* Wf2 = (const float*)d_in[7];
    const float* bf2 = (const float*)d_in[8];
    const int*   ei    = (const int*)d_in[9];
    const int*   batch = (const int*)d_in[10];
    const int* src = ei;        // edge_index row 0
    const int* dst = ei + NE;   // edge_index row 1
    float* out = (float*)d_out;

    const int BT  = 256;
    const int gbN = (NN + BT - 1) / BT;               // 586
    const int gbE = (NE + BT - 1) / BT;               // 18750 (fallback)

    // ---- workspace layout (4-byte words; region starts 16B-aligned) ----
    // mat[512*512] | tot[512] | base[513]pad | ed[NE] | disq[NN] |
    // ybf[NN*H bf16] | bufB[NN*H f32] | g[NG*H]
    size_t need = ((size_t)8821364) * 4;   // ~35.3 MB
    if (ws_size >= need) {
        int*      mat  = (int*)d_ws;                   // 262144
        int*      tot  = mat + 262144;                 // 512
        int*      base = mat + 262656;                 // 513 (pad to 263172)
        unsigned* ed   = (unsigned*)(mat + 263172);    // NE
        float*    disq = (float*)(mat + 5063172);      // NN
        unsigned short* ybf = (unsigned short*)(mat + 5213172); // NN*H bf16
        float*    bufB = (float*)(mat + 6413172);      // NN*H
        float*    g    = (float*)(mat + 8813172);      // NG*H

        // graph bucketing (mat-driven) -> bucket-grouped ed + per-node disq
        k_hist2 <<<NBLK, 512, 0, stream>>>(dst, mat);
        k_scanb <<<NB,   NBLK, 0, stream>>>(mat, tot);
        k_scant <<<1,    NB,  0, stream>>>(tot, base);
        k_part2 <<<NBLK, 512, 0, stream>>>(src, dst, mat, tot, base, ed);
        k_disq_b<<<NB,   512, 0, stream>>>(ed, base, disq);

        // conv1
        k_xw1  <<<gbN, 256, 0, stream>>>(x, W1, disq, ybf);
        k_conv8<<<NB,  512, 0, stream>>>(ed, base, ybf, disq, b1, bufB);   // h1
        // conv2
        k_hw2  <<<gbN, 256, 0, stream>>>(bufB, W2, disq, ybf);             // y2
        k_conv8<<<NB,  512, 0, stream>>>(ed, base, ybf, disq, b2, bufB);   // h2
        // pool + MLP
        k_pool_blk<<<NG, 256, 0, stream>>>(bufB, batch, g);
        k_mlp<<<1, 512, 0, stream>>>(g, Wf1, bf1, Wf2, bf2, out);
    } else {
        // fallback: baseline atomic-scatter path (~20 MB ws, f32)
        float* disq = (float*)d_ws;
        float* bufA = disq + NN;
        float* bufB = bufA + (size_t)NN * H;
        float* g    = bufB + (size_t)NN * H;

        k_deg_init<<<gbN, BT, 0, stream>>>(disq);
        k_deg_edges<<<gbE, BT, 0, stream>>>(dst, disq);
        k_disq<<<gbN, BT, 0, stream>>>(disq);

        k_xw1f<<<gbN, BT, 0, stream>>>(x, W1, disq, bufA);
        hipMemcpyAsync(bufB, bufA, (size_t)NN * H * sizeof(float),
                       hipMemcpyDeviceToDevice, stream);
        k_scatter<<<gbE, BT, 0, stream>>>(src, dst, bufA, bufB);
        k_post<<<gbN, BT, 0, stream>>>(bufB, disq, b1, bufA);

        k_hw2f<<<gbN, BT, 0, stream>>>(bufA, W2, disq, bufB);
        hipMemcpyAsync(bufA, bufB, (size_t)NN * H * sizeof(float),
                       hipMemcpyDeviceToDevice, stream);
        k_scatter<<<gbE, BT, 0, stream>>>(src, dst, bufB, bufA);
        k_post<<<gbN, BT, 0, stream>>>(bufA, disq, b2, bufB);

        k_pool_blk<<<NG, BT, 0, stream>>>(bufB, batch, g);
        k_mlp<<<1, 512, 0, stream>>>(g, Wf1, bf1, Wf2, bf2, out);
    }
}

// Round 20
// 179.769 us; speedup vs baseline: 4.8586x; 4.8586x over previous
//
#include <hip/hip_runtime.h>

constexpr int NN = 150000;   // nodes
constexpr int NE = 4800000;  // edges
constexpr int NG = 512;      // graphs
constexpr int H  = 16;       // hidden
constexpr int NB   = 512;    // coarse dst-buckets
constexpr int NPBK = 293;    // nodes per bucket (512*293 = 150016 >= NN)
constexpr int NBLK = 512;    // streaming blocks for hist/part
constexpr int CHUNK = NE / NBLK;   // 9375 edges per block (exact)
constexpr int CAP = 11776;   // k_csr2 LDS staging capacity (mean 9375, +24 sigma)

__device__ inline unsigned short f2bf(float f) {
    union { float f; unsigned u; } v; v.f = f;
    unsigned r = v.u + 0x7FFFu + ((v.u >> 16) & 1u);   // RNE
    return (unsigned short)(r >> 16);
}
__device__ inline float bf2f(unsigned short s) {
    union { unsigned u; float f; } v; v.u = ((unsigned)s) << 16;
    return v.f;
}

// ---------- phase A: per-block LDS histogram -> mat[b][bucket] ----------
__global__ void k_hist2(const int* __restrict__ dst, int* __restrict__ mat) {
    __shared__ int cnt[NB];
    cnt[threadIdx.x] = 0;
    __syncthreads();
    int b = blockIdx.x;
    int e0 = b * CHUNK, e1 = e0 + CHUNK;
    for (int e = e0 + (int)threadIdx.x; e < e1; e += 512)
        atomicAdd(&cnt[dst[e] / NPBK], 1);
    __syncthreads();
    mat[b * NB + threadIdx.x] = cnt[threadIdx.x];
}

// ---------- column scan: mat[:,j] -> exclusive prefix (in place), totals ----------
__global__ void k_scanb(int* __restrict__ mat, int* __restrict__ tot) {
    __shared__ int tmp[NBLK];
    int j = blockIdx.x, t = threadIdx.x;
    int v = mat[t * NB + j];
    tmp[t] = v;
    __syncthreads();
    for (int off = 1; off < NBLK; off <<= 1) {
        int a = (t >= off) ? tmp[t - off] : 0;
        __syncthreads();
        tmp[t] += a;
        __syncthreads();
    }
    mat[t * NB + j] = tmp[t] - v;               // exclusive within column
    if (t == NBLK - 1) tot[j] = tmp[t];
}

// ---------- bucket base scan (exclusive over NB buckets) ----------
__global__ void k_scant(const int* __restrict__ tot, int* __restrict__ base) {
    __shared__ int tmp[NB];
    int t = threadIdx.x;
    int v = tot[t];
    tmp[t] = v;
    __syncthreads();
    for (int off = 1; off < NB; off <<= 1) {
        int a = (t >= off) ? tmp[t - off] : 0;
        __syncthreads();
        tmp[t] += a;
        __syncthreads();
    }
    base[t] = tmp[t] - v;
    if (t == 0) base[NB] = NE;
}

// ---------- phase B: LDS-staged partition (counts from mat), coalesced writeout ----------
__global__ void k_part2(const int* __restrict__ src, const int* __restrict__ dst,
                        const int* __restrict__ mat, const int* __restrict__ tot,
                        const int* __restrict__ base, unsigned* __restrict__ ed) {
    __shared__ int off[NB];          // exclusive local offsets
    __shared__ int gsnap[NB];        // global run base per bucket
    __shared__ int lcur[NB];         // local scatter cursors
    __shared__ unsigned stg[CHUNK];  // 37.5 KB staging
    int b = blockIdx.x, t = threadIdx.x;
    int e0 = b * CHUNK, e1 = e0 + CHUNK;
    int exg = mat[b * NB + t];                       // col-exclusive (blocks < b)
    int nxt = (b + 1 < NBLK) ? mat[(b + 1) * NB + t] : tot[t];
    int v = nxt - exg;                               // my count for bucket t
    gsnap[t] = base[t] + exg;
    off[t] = v;
    __syncthreads();
    for (int o = 1; o < NB; o <<= 1) {
        int a = (t >= o) ? off[t - o] : 0;
        __syncthreads();
        off[t] += a;
        __syncthreads();
    }
    int excl = off[t] - v;
    __syncthreads();
    off[t]  = excl;
    lcur[t] = excl;
    __syncthreads();
    // scatter into LDS staging (bucket-grouped)
    for (int e = e0 + t; e < e1; e += 512) {
        int d = dst[e];
        int bq = d / NPBK;
        int p = atomicAdd(&lcur[bq], 1);
        stg[p] = (unsigned)src[e] | ((unsigned)(d - bq * NPBK) << 18);
    }
    __syncthreads();
    // writeout: one wave per bucket run, coalesced
    int wave = t >> 6, lane = t & 63;
    for (int bb = wave; bb < NB; bb += 8) {
        int o = off[bb];
        int c = lcur[bb] - o;
        int gb = gsnap[bb];
        for (int k = lane; k < c; k += 64)
            ed[gb + k] = stg[o + k];
    }
}

// ---------- phase B2: per-bucket counting sort, LDS-staged coalesced csr write ----------
__global__ void k_csr2(const unsigned* __restrict__ ed, const int* __restrict__ base,
                       int* __restrict__ rs, int* __restrict__ csr,
                       float* __restrict__ disq) {
    __shared__ int cnt[NB];
    __shared__ int scn[NB];
    __shared__ int stg[CAP];         // 46 KB staging
    int j = blockIdx.x, t = threadIdx.x;
    cnt[t] = 0;
    __syncthreads();
    int e0 = base[j], e1 = base[j + 1];
    int m = e1 - e0;
    for (int e = e0 + t; e < e1; e += 512)
        atomicAdd(&cnt[ed[e] >> 18], 1);
    __syncthreads();
    int v = cnt[t];
    scn[t] = v;
    __syncthreads();
    for (int off = 1; off < NB; off <<= 1) {
        int a = (t >= off) ? scn[t - off] : 0;
        __syncthreads();
        scn[t] += a;
        __syncthreads();
    }
    int excl = scn[t] - v;
    int n0 = j * NPBK;
    int n = n0 + t;
    if (t < NPBK && n < NN) {
        rs[n] = e0 + excl;
        disq[n] = rsqrtf((float)(v + 1));        // +1 self-loop
    }
    cnt[t] = excl;                               // cursors
    __syncthreads();
    if (m <= CAP) {
        for (int e = e0 + t; e < e1; e += 512) {
            unsigned ee = ed[e];
            int p = atomicAdd(&cnt[ee >> 18], 1);
            stg[p] = (int)(ee & 0x3FFFFu);
        }
        __syncthreads();
        for (int k = t; k < m; k += 512) csr[e0 + k] = stg[k];   // coalesced
    } else {
        for (int e = e0 + t; e < e1; e += 512) {
            unsigned ee = ed[e];
            int p = atomicAdd(&cnt[ee >> 18], 1);
            csr[e0 + p] = (int)(ee & 0x3FFFFu);
        }
    }
    if (j == 0 && t == 0) rs[NN] = NE;
}

// ---------- z0 = x * disq -> bf16x4 per node (1.2 MB, L2-resident) ----------
__global__ void k_pre1(const float* __restrict__ x, const float* __restrict__ disq,
                       unsigned short* __restrict__ z0) {
    int i = blockIdx.x * blockDim.x + threadIdx.x;
    if (i >= NN) return;
    float4 xv = ((const float4*)x)[i];
    float d = disq[i];
    unsigned lo = (unsigned)f2bf(xv.x * d) | ((unsigned)f2bf(xv.y * d) << 16);
    unsigned hi = (unsigned)f2bf(xv.z * d) | ((unsigned)f2bf(xv.w * d) << 16);
    ((uint2*)(z0 + (size_t)i * 4))[0] = make_uint2(lo, hi);
}

// ---------- fused conv1: 1 lane/node, gather 4-feature z0, apply W1 in-register ----------
// h1[n] = relu( (disq[n] * (z0[n] + sum z0[src])) @ W1 + b1 )
__global__ void k_gconv1(const int* __restrict__ rs, const int* __restrict__ csr,
                         const unsigned short* __restrict__ z0, const float* __restrict__ disq,
                         const float* __restrict__ W1, const float* __restrict__ b1,
                         float* __restrict__ hout) {
    __shared__ float w[4 * H];
    __shared__ float bs[H];
    if (threadIdx.x < 4 * H) w[threadIdx.x] = W1[threadIdx.x];
    if (threadIdx.x < H) bs[threadIdx.x] = b1[threadIdx.x];
    __syncthreads();
    int n = blockIdx.x * blockDim.x + threadIdx.x;
    if (n >= NN) return;
    int s0 = rs[n], s1 = rs[n + 1];
    uint2 zs = ((const uint2*)(z0 + (size_t)n * 4))[0];      // self-loop
    float a0 = bf2f((unsigned short)(zs.x & 0xFFFF));
    float a1 = bf2f((unsigned short)(zs.x >> 16));
    float a2 = bf2f((unsigned short)(zs.y & 0xFFFF));
    float a3 = bf2f((unsigned short)(zs.y >> 16));
    int k = s0;
    for (; k + 8 <= s1; k += 8) {
        int i0 = csr[k+0], i1 = csr[k+1], i2 = csr[k+2], i3 = csr[k+3];
        int i4 = csr[k+4], i5 = csr[k+5], i6 = csr[k+6], i7 = csr[k+7];
        uint2 v0 = ((const uint2*)(z0 + (size_t)i0 * 4))[0];
        uint2 v1 = ((const uint2*)(z0 + (size_t)i1 * 4))[0];
        uint2 v2 = ((const uint2*)(z0 + (size_t)i2 * 4))[0];
        uint2 v3 = ((const uint2*)(z0 + (size_t)i3 * 4))[0];
        uint2 v4 = ((const uint2*)(z0 + (size_t)i4 * 4))[0];
        uint2 v5 = ((const uint2*)(z0 + (size_t)i5 * 4))[0];
        uint2 v6 = ((const uint2*)(z0 + (size_t)i6 * 4))[0];
        uint2 v7 = ((const uint2*)(z0 + (size_t)i7 * 4))[0];
#define ACC4(vv) { \
        a0 += bf2f((unsigned short)(vv.x & 0xFFFF)); \
        a1 += bf2f((unsigned short)(vv.x >> 16)); \
        a2 += bf2f((unsigned short)(vv.y & 0xFFFF)); \
        a3 += bf2f((unsigned short)(vv.y >> 16)); }
        ACC4(v0) ACC4(v1) ACC4(v2) ACC4(v3) ACC4(v4) ACC4(v5) ACC4(v6) ACC4(v7)
    }
    for (; k < s1; ++k) {
        uint2 v = ((const uint2*)(z0 + (size_t)csr[k] * 4))[0];
        ACC4(v)
    }
#undef ACC4
    float d = disq[n];
    a0 *= d; a1 *= d; a2 *= d; a3 *= d;
    float o[H];
#pragma unroll
    for (int h = 0; h < H; ++h)
        o[h] = fmaxf(a0 * w[0*H + h] + a1 * w[1*H + h] +
                     a2 * w[2*H + h] + a3 * w[3*H + h] + bs[h], 0.f);
    float4* hp = (float4*)(hout + (size_t)n * H);
#pragma unroll
    for (int q = 0; q < 4; ++q) hp[q] = ((float4*)o)[q];
}

// ---------- gather (conv2): 16 lanes/node, 8-way unrolled ----------
__global__ void k_gather(const int* __restrict__ rs, const int* __restrict__ csr,
                         const unsigned short* __restrict__ y, const float* __restrict__ disq,
                         const float* __restrict__ b, float* __restrict__ hout) {
    int n    = blockIdx.x * 16 + (threadIdx.x >> 4);
    int lane = threadIdx.x & 15;
    if (n >= NN) return;
    int s0 = rs[n], s1 = rs[n + 1];
    float acc = bf2f(y[(size_t)n * H + lane]);   // self-loop term
    int k = s0;
    for (; k + 8 <= s1; k += 8) {
        int sa = csr[k+0], sb = csr[k+1], sc = csr[k+2], sd = csr[k+3];
        int se = csr[k+4], sf = csr[k+5], sg = csr[k+6], sh = csr[k+7];
        float v0 = bf2f(y[(size_t)sa * H + lane]);
        float v1 = bf2f(y[(size_t)sb * H + lane]);
        float v2 = bf2f(y[(size_t)sc * H + lane]);
        float v3 = bf2f(y[(size_t)sd * H + lane]);
        float v4 = bf2f(y[(size_t)se * H + lane]);
        float v5 = bf2f(y[(size_t)sf * H + lane]);
        float v6 = bf2f(y[(size_t)sg * H + lane]);
        float v7 = bf2f(y[(size_t)sh * H + lane]);
        acc += ((v0 + v1) + (v2 + v3)) + ((v4 + v5) + (v6 + v7));
    }
    for (; k < s1; ++k) acc += bf2f(y[(size_t)csr[k] * H + lane]);
    hout[(size_t)n * H + lane] = fmaxf(fmaf(acc, disq[n], b[lane]), 0.f);
}

// ---------- y = (h @ W2) * disq -> bf16 ----------
__global__ void k_hw2(const float* __restrict__ hin, const float* __restrict__ W2,
                      const float* __restrict__ disq, unsigned short* __restrict__ yout) {
    __shared__ float w[H * H];
    if (threadIdx.x < H * H) w[threadIdx.x] = W2[threadIdx.x];
    __syncthreads();
    int i = blockIdx.x * blockDim.x + threadIdx.x;
    if (i >= NN) return;
    float hv[H];
    const float4* hp = (const float4*)(hin + (size_t)i * H);
#pragma unroll
    for (int q = 0; q < 4; ++q) ((float4*)hv)[q] = hp[q];
    float d = disq[i];
    float o[H];
#pragma unroll
    for (int h = 0; h < H; ++h) {
        float s = 0.f;
#pragma unroll
        for (int k = 0; k < H; ++k) s += hv[k] * w[k*H + h];
        o[h] = s * d;
    }
    unsigned pk[8];
#pragma unroll
    for (int q = 0; q < 8; ++q)
        pk[q] = (unsigned)f2bf(o[2*q]) | ((unsigned)f2bf(o[2*q+1]) << 16);
    uint4* yp = (uint4*)(yout + (size_t)i * H);
    yp[0] = make_uint4(pk[0], pk[1], pk[2], pk[3]);
    yp[1] = make_uint4(pk[4], pk[5], pk[6], pk[7]);
}

// ---------- pool: one block per graph, 16 groups x 16 lanes + LDS tree ----------
__global__ void k_pool_blk(const float* __restrict__ h, const int* __restrict__ batch,
                           float* __restrict__ gout) {
    __shared__ float red[16][H + 1];
    int g    = blockIdx.x;
    int lane = threadIdx.x & 15;
    int grp  = threadIdx.x >> 4;                 // 0..15
    int lo = 0, hi = NN;
    while (lo < hi) { int m = (lo + hi) >> 1; if (batch[m] < g) lo = m + 1; else hi = m; }
    int start = lo;
    hi = NN;
    while (lo < hi) { int m = (lo + hi) >> 1; if (batch[m] < g + 1) lo = m + 1; else hi = m; }
    int end = lo;
    float acc = 0.f;
    for (int i = start + grp; i < end; i += 16)
        acc += h[(size_t)i * H + lane];
    red[grp][lane] = acc;
    __syncthreads();
    if (grp < 8) red[grp][lane] += red[grp + 8][lane];
    __syncthreads();
    if (grp < 4) red[grp][lane] += red[grp + 4][lane];
    __syncthreads();
    if (grp < 2) red[grp][lane] += red[grp + 2][lane];
    __syncthreads();
    if (grp == 0)
        gout[(size_t)g * H + lane] = red[0][lane] + red[1][lane];
}

// ---------- final MLP ----------
__global__ void k_mlp(const float* __restrict__ g, const float* __restrict__ Wf1,
                      const float* __restrict__ bf1, const float* __restrict__ Wf2,
                      const float* __restrict__ bf2, float* __restrict__ out) {
    __shared__ float w1[H * H];
    __shared__ float b1s[H];
    __shared__ float w2[H];
    __shared__ float b2s;
    if (threadIdx.x < H * H) w1[threadIdx.x] = Wf1[threadIdx.x];
    if (threadIdx.x < H) { b1s[threadIdx.x] = bf1[threadIdx.x]; w2[threadIdx.x] = Wf2[threadIdx.x]; }
    if (threadIdx.x == 0) b2s = bf2[0];
    __syncthreads();
    int i = blockIdx.x * blockDim.x + threadIdx.x;
    if (i >= NG) return;
    float gv[H];
    const float4* gp = (const float4*)(g + (size_t)i * H);
#pragma unroll
    for (int q = 0; q < 4; ++q) ((float4*)gv)[q] = gp[q];
    float s2 = 0.f;
#pragma unroll
    for (int h = 0; h < H; ++h) {
        float t = b1s[h];
#pragma unroll
        for (int k = 0; k < H; ++k) t += gv[k] * w1[k*H + h];
        s2 += fmaxf(t, 0.f) * w2[h];
    }
    out[i] = s2 + b2s;
}

// ================= fallback (baseline atomic path, f32) =================
__global__ void k_deg_init(float* __restrict__ deg) {
    int i = blockIdx.x * blockDim.x + threadIdx.x;
    if (i < NN) deg[i] = 1.0f;
}
__global__ void k_deg_edges(const int* __restrict__ dst, float* __restrict__ deg) {
    int i = blockIdx.x * blockDim.x + threadIdx.x;
    if (i < NE) atomicAdd(&deg[dst[i]], 1.0f);
}
__global__ void k_disq(float* __restrict__ deg) {
    int i = blockIdx.x * blockDim.x + threadIdx.x;
    if (i < NN) deg[i] = rsqrtf(deg[i]);
}
__global__ void k_xw1f(const float* __restrict__ x, const float* __restrict__ W1,
                       const float* __restrict__ disq, float* __restrict__ y) {
    __shared__ float w[4 * H];
    if (threadIdx.x < 4 * H) w[threadIdx.x] = W1[threadIdx.x];
    __syncthreads();
    int i = blockIdx.x * blockDim.x + threadIdx.x;
    if (i >= NN) return;
    float4 xv = ((const float4*)x)[i];
    float d = disq[i];
    float o[H];
#pragma unroll
    for (int h = 0; h < H; ++h)
        o[h] = (xv.x * w[0*H + h] + xv.y * w[1*H + h] +
                xv.z * w[2*H + h] + xv.w * w[3*H + h]) * d;
    float4* yp = (float4*)(y + (size_t)i * H);
#pragma unroll
    for (int q = 0; q < 4; ++q) yp[q] = ((float4*)o)[q];
}
__global__ void k_hw2f(const float* __restrict__ hin, const float* __restrict__ W2,
                       const float* __restrict__ disq, float* __restrict__ yout) {
    __shared__ float w[H * H];
    if (threadIdx.x < H * H) w[threadIdx.x] = W2[threadIdx.x];
    __syncthreads();
    int i = blockIdx.x * blockDim.x + threadIdx.x;
    if (i >= NN) return;
    float hv[H];
    const float4* hp = (const float4*)(hin + (size_t)i * H);
#pragma unroll
    for (int q = 0; q < 4; ++q) ((float4*)hv)[q] = hp[q];
    float d = disq[i];
    float o[H];
#pragma unroll
    for (int h = 0; h < H; ++h) {
        float s = 0.f;
#pragma unroll
        for (int k = 0; k < H; ++k) s += hv[k] * w[k*H + h];
        o[h] = s * d;
    }
    float4* yp = (float4*)(yout + (size_t)i * H);
#pragma unroll
    for (int q = 0; q < 4; ++q) yp[q] = ((float4*)o)[q];
}
__global__ void k_scatter(const int* __restrict__ src, const int* __restrict__ dst,
                          const float* __restrict__ y, float* __restrict__ acc) {
    int i = blockIdx.x * blockDim.x + threadIdx.x;
    if (i >= NE) return;
    int s = src[i], d = dst[i];
    const float4* yp = (const float4*)(y + (size_t)s * H);
    float* ap = acc + (size_t)d * H;
#pragma unroll
    for (int q = 0; q < 4; ++q) {
        float4 v = yp[q];
        atomicAdd(ap + q*4 + 0, v.x);
        atomicAdd(ap + q*4 + 1, v.y);
        atomicAdd(ap + q*4 + 2, v.z);
        atomicAdd(ap + q*4 + 3, v.w);
    }
}
__global__ void k_post(const float* __restrict__ acc, const float* __restrict__ disq,
                       const float* __restrict__ b, float* __restrict__ hout) {
    __shared__ float bs[H];
    if (threadIdx.x < H) bs[threadIdx.x] = b[threadIdx.x];
    __syncthreads();
    int i = blockIdx.x * blockDim.x + threadIdx.x;
    if (i >= NN) return;
    float d = disq[i];
    const float4* ap = (const float4*)(acc + (size_t)i * H);
    float4* hp = (float4*)(hout + (size_t)i * H);
#pragma unroll
    for (int q = 0; q < 4; ++q) {
        float4 v = ap[q];
        float4 r;
        r.x = fmaxf(v.x * d + bs[q*4+0], 0.f);
        r.y = fmaxf(v.y * d + bs[q*4+1], 0.f);
        r.z = fmaxf(v.z * d + bs[q*4+2], 0.f);
        r.w = fmaxf(v.w * d + bs[q*4+3], 0.f);
        hp[q] = r;
    }
}

extern "C" void kernel_launch(void* const* d_in, const int* in_sizes, int n_in,
                              void* d_out, int out_size, void* d_ws, size_t ws_size,
                              hipStream_t stream) {
    const float* x   = (const float*)d_in[0];
    const float* W1  = (const float*)d_in[1];
    const float* b1  = (const float*)d_in[2];
    const float* W2  = (const float*)d_in[3];
    const float* b2  = (const float*)d_in[4];
    const float* Wf1 = (const float*)d_in[5];
    const float* bf1 = (const float*)d_in[6];
    const float* Wf2 = (const float*)d_in[7];
    const float* bf2 = (const float*)d_in[8];
    const int*   ei    = (const int*)d_in[9];
    const int*   batch = (const int*)d_in[10];
    const int* src = ei;        // edge_index row 0
    const int* dst = ei + NE;   // edge_index row 1
    float* out = (float*)d_out;

    const int BT  = 256;
    const int gbN = (NN + BT - 1) / BT;               // 586
    const int gbE = (NE + BT - 1) / BT;               // 18750 (fallback)
    const int NPB = BT / H;                           // 16
    const int gbG = (NN + NPB - 1) / NPB;             // 9375 gather blocks

    // ---- workspace layout (4-byte words; region starts 16B-aligned) ----
    // mat[512*512] | tot[512] | base[513]pad | ed[NE] | csr[NE] | rs[NN+1]pad |
    // disq[NN] | ybf[NN*H bf16] (z0 overlaps its first 300000 words) |
    // bufB[NN*H f32] | g[NG*H]
    size_t need = ((size_t)13771368) * 4;   // ~55.1 MB
    if (ws_size >= need) {
        int*      mat  = (int*)d_ws;                   // 262144
        int*      tot  = mat + 262144;                 // 512
        int*      base = mat + 262656;                 // 513 (pad to 263172)
        unsigned* ed   = (unsigned*)(mat + 263172);    // NE
        int*      csr  = mat + 5063172;                // NE
        int*      rs   = mat + 9863172;                // NN+1 (pad to 10013176)
        float*    disq = (float*)(mat + 10013176);     // NN
        unsigned short* ybf = (unsigned short*)(mat + 10163176); // NN*H bf16
        unsigned short* z0  = ybf;                     // N*4 bf16, overlaps (used before hw2)
        float*    bufB = (float*)(mat + 11363176);     // NN*H
        float*    g    = (float*)(mat + 13763176);     // NG*H

        // graph bucketing (mat-driven) -> CSR
        k_hist2<<<NBLK, 512, 0, stream>>>(dst, mat);
        k_scanb<<<NB,   NBLK, 0, stream>>>(mat, tot);
        k_scant<<<1,    NB,  0, stream>>>(tot, base);
        k_part2<<<NBLK, 512, 0, stream>>>(src, dst, mat, tot, base, ed);
        k_csr2 <<<NB,   512, 0, stream>>>(ed, base, rs, csr, disq);

        // conv1: aggregate 4-feature z0 (L2-resident), apply W1 post-agg
        k_pre1  <<<gbN, 256, 0, stream>>>(x, disq, z0);
        k_gconv1<<<gbN, 256, 0, stream>>>(rs, csr, z0, disq, W1, b1, bufB);   // h1
        // conv2
        k_hw2   <<<gbN, 256, 0, stream>>>(bufB, W2, disq, ybf);               // y2
        k_gather<<<gbG, 256, 0, stream>>>(rs, csr, ybf, disq, b2, bufB);      // h2
        // pool + MLP
        k_pool_blk<<<NG, 256, 0, stream>>>(bufB, batch, g);
        k_mlp<<<1, 512, 0, stream>>>(g, Wf1, bf1, Wf2, bf2, out);
    } else {
        // fallback: baseline atomic-scatter path (~20 MB ws, f32)
        float* disq = (float*)d_ws;
        float* bufA = disq + NN;
        float* bufB = bufA + (size_t)NN * H;
        float* g    = bufB + (size_t)NN * H;

        k_deg_init<<<gbN, BT, 0, stream>>>(disq);
        k_deg_edges<<<gbE, BT, 0, stream>>>(dst, disq);
        k_disq<<<gbN, BT, 0, stream>>>(disq);

        k_xw1f<<<gbN, BT, 0, stream>>>(x, W1, disq, bufA);
        hipMemcpyAsync(bufB, bufA, (size_t)NN * H * sizeof(float),
                       hipMemcpyDeviceToDevice, stream);
        k_scatter<<<gbE, BT, 0, stream>>>(src, dst, bufA, bufB);
        k_post<<<gbN, BT, 0, stream>>>(bufB, disq, b1, bufA);

        k_hw2f<<<gbN, BT, 0, stream>>>(bufA, W2, disq, bufB);
        hipMemcpyAsync(bufA, bufB, (size_t)NN * H * sizeof(float),
                       hipMemcpyDeviceToDevice, stream);
        k_scatter<<<gbE, BT, 0, stream>>>(src, dst, bufB, bufA);
        k_post<<<gbN, BT, 0, stream>>>(bufA, disq, b2, bufB);

        k_pool_blk<<<NG, BT, 0, stream>>>(bufB, batch, g);
        k_mlp<<<1, 512, 0, stream>>>(g, Wf1, bf1, Wf2, bf2, out);
    }
}

// Round 21
// 171.436 us; speedup vs baseline: 5.0947x; 1.0486x over previous
//
#include <hip/hip_runtime.h>

constexpr int NN = 150000;   // nodes
constexpr int NE = 4800000;  // edges
constexpr int NG = 512;      // graphs
constexpr int H  = 16;       // hidden
constexpr int NB   = 512;    // coarse dst-buckets
constexpr int NPBK = 293;    // nodes per bucket (512*293 = 150016 >= NN)
constexpr int NBLK = 512;    // streaming blocks for hist/part
constexpr int CHUNK = NE / NBLK;   // 9375 edges per block (exact)
constexpr int CAP = 11776;   // k_csr2 LDS staging capacity (mean 9375, +24 sigma)

__device__ inline unsigned short f2bf(float f) {
    union { float f; unsigned u; } v; v.f = f;
    unsigned r = v.u + 0x7FFFu + ((v.u >> 16) & 1u);   // RNE
    return (unsigned short)(r >> 16);
}
__device__ inline float bf2f(unsigned short s) {
    union { unsigned u; float f; } v; v.u = ((unsigned)s) << 16;
    return v.f;
}

// ---------- phase A: per-block LDS histogram -> mat[b][bucket] ----------
__global__ void k_hist2(const int* __restrict__ dst, int* __restrict__ mat) {
    __shared__ int cnt[NB];
    cnt[threadIdx.x] = 0;
    __syncthreads();
    int b = blockIdx.x;
    int e0 = b * CHUNK, e1 = e0 + CHUNK;
    for (int e = e0 + (int)threadIdx.x; e < e1; e += 512)
        atomicAdd(&cnt[dst[e] / NPBK], 1);
    __syncthreads();
    mat[b * NB + threadIdx.x] = cnt[threadIdx.x];
}

// ---------- column scan: mat[:,j] -> exclusive prefix (in place), totals ----------
__global__ void k_scanb(int* __restrict__ mat, int* __restrict__ tot) {
    __shared__ int tmp[NBLK];
    int j = blockIdx.x, t = threadIdx.x;
    int v = mat[t * NB + j];
    tmp[t] = v;
    __syncthreads();
    for (int off = 1; off < NBLK; off <<= 1) {
        int a = (t >= off) ? tmp[t - off] : 0;
        __syncthreads();
        tmp[t] += a;
        __syncthreads();
    }
    mat[t * NB + j] = tmp[t] - v;               // exclusive within column
    if (t == NBLK - 1) tot[j] = tmp[t];
}

// ---------- bucket base scan (exclusive over NB buckets) ----------
__global__ void k_scant(const int* __restrict__ tot, int* __restrict__ base) {
    __shared__ int tmp[NB];
    int t = threadIdx.x;
    int v = tot[t];
    tmp[t] = v;
    __syncthreads();
    for (int off = 1; off < NB; off <<= 1) {
        int a = (t >= off) ? tmp[t - off] : 0;
        __syncthreads();
        tmp[t] += a;
        __syncthreads();
    }
    base[t] = tmp[t] - v;
    if (t == 0) base[NB] = NE;
}

// ---------- phase B: LDS-staged partition (counts from mat), coalesced writeout ----------
__global__ void k_part2(const int* __restrict__ src, const int* __restrict__ dst,
                        const int* __restrict__ mat, const int* __restrict__ tot,
                        const int* __restrict__ base, unsigned* __restrict__ ed) {
    __shared__ int off[NB];          // exclusive local offsets
    __shared__ int gsnap[NB];        // global run base per bucket
    __shared__ int lcur[NB];         // local scatter cursors
    __shared__ unsigned stg[CHUNK];  // 37.5 KB staging
    int b = blockIdx.x, t = threadIdx.x;
    int e0 = b * CHUNK, e1 = e0 + CHUNK;
    int exg = mat[b * NB + t];                       // col-exclusive (blocks < b)
    int nxt = (b + 1 < NBLK) ? mat[(b + 1) * NB + t] : tot[t];
    int v = nxt - exg;                               // my count for bucket t
    gsnap[t] = base[t] + exg;
    off[t] = v;
    __syncthreads();
    for (int o = 1; o < NB; o <<= 1) {
        int a = (t >= o) ? off[t - o] : 0;
        __syncthreads();
        off[t] += a;
        __syncthreads();
    }
    int excl = off[t] - v;
    __syncthreads();
    off[t]  = excl;
    lcur[t] = excl;
    __syncthreads();
    // scatter into LDS staging (bucket-grouped)
    for (int e = e0 + t; e < e1; e += 512) {
        int d = dst[e];
        int bq = d / NPBK;
        int p = atomicAdd(&lcur[bq], 1);
        stg[p] = (unsigned)src[e] | ((unsigned)(d - bq * NPBK) << 18);
    }
    __syncthreads();
    // writeout: one wave per bucket run, coalesced
    int wave = t >> 6, lane = t & 63;
    for (int bb = wave; bb < NB; bb += 8) {
        int o = off[bb];
        int c = lcur[bb] - o;
        int gb = gsnap[bb];
        for (int k = lane; k < c; k += 64)
            ed[gb + k] = stg[o + k];
    }
}

// ---------- phase B2: counting sort -> CSR + disq + z0 = bf16(x*disq) ----------
__global__ void k_csr2(const unsigned* __restrict__ ed, const int* __restrict__ base,
                       const float* __restrict__ x,
                       int* __restrict__ rs, int* __restrict__ csr,
                       float* __restrict__ disq, unsigned short* __restrict__ z0) {
    __shared__ int cnt[NB];
    __shared__ int scn[NB];
    __shared__ int stg[CAP];         // 46 KB staging
    int j = blockIdx.x, t = threadIdx.x;
    cnt[t] = 0;
    __syncthreads();
    int e0 = base[j], e1 = base[j + 1];
    int m = e1 - e0;
    for (int e = e0 + t; e < e1; e += 512)
        atomicAdd(&cnt[ed[e] >> 18], 1);
    __syncthreads();
    int v = cnt[t];
    scn[t] = v;
    __syncthreads();
    for (int off = 1; off < NB; off <<= 1) {
        int a = (t >= off) ? scn[t - off] : 0;
        __syncthreads();
        scn[t] += a;
        __syncthreads();
    }
    int excl = scn[t] - v;
    int n0 = j * NPBK;
    int n = n0 + t;
    if (t < NPBK && n < NN) {
        rs[n] = e0 + excl;
        float dq = rsqrtf((float)(v + 1));       // +1 self-loop
        disq[n] = dq;
        float4 xv = ((const float4*)x)[n];
        unsigned lo = (unsigned)f2bf(xv.x * dq) | ((unsigned)f2bf(xv.y * dq) << 16);
        unsigned hi = (unsigned)f2bf(xv.z * dq) | ((unsigned)f2bf(xv.w * dq) << 16);
        ((uint2*)(z0 + (size_t)n * 4))[0] = make_uint2(lo, hi);
    }
    cnt[t] = excl;                               // cursors
    __syncthreads();
    if (m <= CAP) {
        for (int e = e0 + t; e < e1; e += 512) {
            unsigned ee = ed[e];
            int p = atomicAdd(&cnt[ee >> 18], 1);
            stg[p] = (int)(ee & 0x3FFFFu);
        }
        __syncthreads();
        for (int k = t; k < m; k += 512) csr[e0 + k] = stg[k];   // coalesced
    } else {
        for (int e = e0 + t; e < e1; e += 512) {
            unsigned ee = ed[e];
            int p = atomicAdd(&cnt[ee >> 18], 1);
            csr[e0 + p] = (int)(ee & 0x3FFFFu);
        }
    }
    if (j == 0 && t == 0) rs[NN] = NE;
}

// ---------- fused conv1+W2: gather z0 (L2-resident), h1 in regs, emit y2 bf16 ----------
// h1 = relu((disq*(z0[n]+sum z0[src])) @ W1 + b1);  y2 = (h1 @ W2) * disq -> bf16
__global__ void k_gconv12(const int* __restrict__ rs, const int* __restrict__ csr,
                          const unsigned short* __restrict__ z0, const float* __restrict__ disq,
                          const float* __restrict__ W1, const float* __restrict__ b1,
                          const float* __restrict__ W2, unsigned short* __restrict__ yout) {
    __shared__ float w[4 * H];
    __shared__ float bs[H];
    __shared__ float w2[H * H];
    if (threadIdx.x < 4 * H) w[threadIdx.x] = W1[threadIdx.x];
    if (threadIdx.x < H) bs[threadIdx.x] = b1[threadIdx.x];
    if (threadIdx.x < H * H) w2[threadIdx.x] = W2[threadIdx.x];
    __syncthreads();
    int n = blockIdx.x * blockDim.x + threadIdx.x;
    if (n >= NN) return;
    int s0 = rs[n], s1 = rs[n + 1];
    uint2 zs = ((const uint2*)(z0 + (size_t)n * 4))[0];      // self-loop
    float a0 = bf2f((unsigned short)(zs.x & 0xFFFF));
    float a1 = bf2f((unsigned short)(zs.x >> 16));
    float a2 = bf2f((unsigned short)(zs.y & 0xFFFF));
    float a3 = bf2f((unsigned short)(zs.y >> 16));
    int k = s0;
    for (; k + 8 <= s1; k += 8) {
        int i0 = csr[k+0], i1 = csr[k+1], i2 = csr[k+2], i3 = csr[k+3];
        int i4 = csr[k+4], i5 = csr[k+5], i6 = csr[k+6], i7 = csr[k+7];
        uint2 v0 = ((const uint2*)(z0 + (size_t)i0 * 4))[0];
        uint2 v1 = ((const uint2*)(z0 + (size_t)i1 * 4))[0];
        uint2 v2 = ((const uint2*)(z0 + (size_t)i2 * 4))[0];
        uint2 v3 = ((const uint2*)(z0 + (size_t)i3 * 4))[0];
        uint2 v4 = ((const uint2*)(z0 + (size_t)i4 * 4))[0];
        uint2 v5 = ((const uint2*)(z0 + (size_t)i5 * 4))[0];
        uint2 v6 = ((const uint2*)(z0 + (size_t)i6 * 4))[0];
        uint2 v7 = ((const uint2*)(z0 + (size_t)i7 * 4))[0];
#define ACC4(vv) { \
        a0 += bf2f((unsigned short)(vv.x & 0xFFFF)); \
        a1 += bf2f((unsigned short)(vv.x >> 16)); \
        a2 += bf2f((unsigned short)(vv.y & 0xFFFF)); \
        a3 += bf2f((unsigned short)(vv.y >> 16)); }
        ACC4(v0) ACC4(v1) ACC4(v2) ACC4(v3) ACC4(v4) ACC4(v5) ACC4(v6) ACC4(v7)
    }
    for (; k < s1; ++k) {
        uint2 v = ((const uint2*)(z0 + (size_t)csr[k] * 4))[0];
        ACC4(v)
    }
#undef ACC4
    float d = disq[n];
    a0 *= d; a1 *= d; a2 *= d; a3 *= d;
    float o[H];
#pragma unroll
    for (int h = 0; h < H; ++h)
        o[h] = fmaxf(a0 * w[0*H + h] + a1 * w[1*H + h] +
                     a2 * w[2*H + h] + a3 * w[3*H + h] + bs[h], 0.f);
    // fused hw2: y2 = (h1 @ W2) * disq -> bf16
    float o2[H];
#pragma unroll
    for (int h = 0; h < H; ++h) {
        float s = 0.f;
#pragma unroll
        for (int kk = 0; kk < H; ++kk) s += o[kk] * w2[kk*H + h];
        o2[h] = s * d;
    }
    unsigned pk[8];
#pragma unroll
    for (int q = 0; q < 8; ++q)
        pk[q] = (unsigned)f2bf(o2[2*q]) | ((unsigned)f2bf(o2[2*q+1]) << 16);
    uint4* yp = (uint4*)(yout + (size_t)n * H);
    yp[0] = make_uint4(pk[0], pk[1], pk[2], pk[3]);
    yp[1] = make_uint4(pk[4], pk[5], pk[6], pk[7]);
}

// ---------- gather (conv2): 16 lanes/node, 8-way unrolled ----------
__global__ void k_gather(const int* __restrict__ rs, const int* __restrict__ csr,
                         const unsigned short* __restrict__ y, const float* __restrict__ disq,
                         const float* __restrict__ b, float* __restrict__ hout) {
    int n    = blockIdx.x * 16 + (threadIdx.x >> 4);
    int lane = threadIdx.x & 15;
    if (n >= NN) return;
    int s0 = rs[n], s1 = rs[n + 1];
    float acc = bf2f(y[(size_t)n * H + lane]);   // self-loop term
    int k = s0;
    for (; k + 8 <= s1; k += 8) {
        int sa = csr[k+0], sb = csr[k+1], sc = csr[k+2], sd = csr[k+3];
        int se = csr[k+4], sf = csr[k+5], sg = csr[k+6], sh = csr[k+7];
        float v0 = bf2f(y[(size_t)sa * H + lane]);
        float v1 = bf2f(y[(size_t)sb * H + lane]);
        float v2 = bf2f(y[(size_t)sc * H + lane]);
        float v3 = bf2f(y[(size_t)sd * H + lane]);
        float v4 = bf2f(y[(size_t)se * H + lane]);
        float v5 = bf2f(y[(size_t)sf * H + lane]);
        float v6 = bf2f(y[(size_t)sg * H + lane]);
        float v7 = bf2f(y[(size_t)sh * H + lane]);
        acc += ((v0 + v1) + (v2 + v3)) + ((v4 + v5) + (v6 + v7));
    }
    for (; k < s1; ++k) acc += bf2f(y[(size_t)csr[k] * H + lane]);
    hout[(size_t)n * H + lane] = fmaxf(fmaf(acc, disq[n], b[lane]), 0.f);
}

// ---------- pool: one block per graph, 16 groups x 16 lanes + LDS tree ----------
__global__ void k_pool_blk(const float* __restrict__ h, const int* __restrict__ batch,
                           float* __restrict__ gout) {
    __shared__ float red[16][H + 1];
    int g    = blockIdx.x;
    int lane = threadIdx.x & 15;
    int grp  = threadIdx.x >> 4;                 // 0..15
    int lo = 0, hi = NN;
    while (lo < hi) { int m = (lo + hi) >> 1; if (batch[m] < g) lo = m + 1; else hi = m; }
    int start = lo;
    hi = NN;
    while (lo < hi) { int m = (lo + hi) >> 1; if (batch[m] < g + 1) lo = m + 1; else hi = m; }
    int end = lo;
    float acc = 0.f;
    for (int i = start + grp; i < end; i += 16)
        acc += h[(size_t)i * H + lane];
    red[grp][lane] = acc;
    __syncthreads();
    if (grp < 8) red[grp][lane] += red[grp + 8][lane];
    __syncthreads();
    if (grp < 4) red[grp][lane] += red[grp + 4][lane];
    __syncthreads();
    if (grp < 2) red[grp][lane] += red[grp + 2][lane];
    __syncthreads();
    if (grp == 0)
        gout[(size_t)g * H + lane] = red[0][lane] + red[1][lane];
}

// ---------- final MLP ----------
__global__ void k_mlp(const float* __restrict__ g, const float* __restrict__ Wf1,
                      const float* __restrict__ bf1, const float* __restrict__ Wf2,
                      const float* __restrict__ bf2, float* __restrict__ out) {
    __shared__ float w1[H * H];
    __shared__ float b1s[H];
    __shared__ float w2[H];
    __shared__ float b2s;
    if (threadIdx.x < H * H) w1[threadIdx.x] = Wf1[threadIdx.x];
    if (threadIdx.x < H) { b1s[threadIdx.x] = bf1[threadIdx.x]; w2[threadIdx.x] = Wf2[threadIdx.x]; }
    if (threadIdx.x == 0) b2s = bf2[0];
    __syncthreads();
    int i = blockIdx.x * blockDim.x + threadIdx.x;
    if (i >= NG) return;
    float gv[H];
    const float4* gp = (const float4*)(g + (size_t)i * H);
#pragma unroll
    for (int q = 0; q < 4; ++q) ((float4*)gv)[q] = gp[q];
    float s2 = 0.f;
#pragma unroll
    for (int h = 0; h < H; ++h) {
        float t = b1s[h];
#pragma unroll
        for (int k = 0; k < H; ++k) t += gv[k] * w1[k*H + h];
        s2 += fmaxf(t, 0.f) * w2[h];
    }
    out[i] = s2 + b2s;
}

// ================= fallback (baseline atomic path, f32) =================
__global__ void k_deg_init(float* __restrict__ deg) {
    int i = blockIdx.x * blockDim.x + threadIdx.x;
    if (i < NN) deg[i] = 1.0f;
}
__global__ void k_deg_edges(const int* __restrict__ dst, float* __restrict__ deg) {
    int i = blockIdx.x * blockDim.x + threadIdx.x;
    if (i < NE) atomicAdd(&deg[dst[i]], 1.0f);
}
__global__ void k_disq(float* __restrict__ deg) {
    int i = blockIdx.x * blockDim.x + threadIdx.x;
    if (i < NN) deg[i] = rsqrtf(deg[i]);
}
__global__ void k_xw1f(const float* __restrict__ x, const float* __restrict__ W1,
                       const float* __restrict__ disq, float* __restrict__ y) {
    __shared__ float w[4 * H];
    if (threadIdx.x < 4 * H) w[threadIdx.x] = W1[threadIdx.x];
    __syncthreads();
    int i = blockIdx.x * blockDim.x + threadIdx.x;
    if (i >= NN) return;
    float4 xv = ((const float4*)x)[i];
    float d = disq[i];
    float o[H];
#pragma unroll
    for (int h = 0; h < H; ++h)
        o[h] = (xv.x * w[0*H + h] + xv.y * w[1*H + h] +
                xv.z * w[2*H + h] + xv.w * w[3*H + h]) * d;
    float4* yp = (float4*)(y + (size_t)i * H);
#pragma unroll
    for (int q = 0; q < 4; ++q) yp[q] = ((float4*)o)[q];
}
__global__ void k_hw2f(const float* __restrict__ hin, const float* __restrict__ W2,
                       const float* __restrict__ disq, float* __restrict__ yout) {
    __shared__ float w[H * H];
    if (threadIdx.x < H * H) w[threadIdx.x] = W2[threadIdx.x];
    __syncthreads();
    int i = blockIdx.x * blockDim.x + threadIdx.x;
    if (i >= NN) return;
    float hv[H];
    const float4* hp = (const float4*)(hin + (size_t)i * H);
#pragma unroll
    for (int q = 0; q < 4; ++q) ((float4*)hv)[q] = hp[q];
    float d = disq[i];
    float o[H];
#pragma unroll
    for (int h = 0; h < H; ++h) {
        float s = 0.f;
#pragma unroll
        for (int k = 0; k < H; ++k) s += hv[k] * w[k*H + h];
        o[h] = s * d;
    }
    float4* yp = (float4*)(yout + (size_t)i * H);
#pragma unroll
    for (int q = 0; q < 4; ++q) yp[q] = ((float4*)o)[q];
}
__global__ void k_scatter(const int* __restrict__ src, const int* __restrict__ dst,
                          const float* __restrict__ y, float* __restrict__ acc) {
    int i = blockIdx.x * blockDim.x + threadIdx.x;
    if (i >= NE) return;
    int s = src[i], d = dst[i];
    const float4* yp = (const float4*)(y + (size_t)s * H);
    float* ap = acc + (size_t)d * H;
#pragma unroll
    for (int q = 0; q < 4; ++q) {
        float4 v = yp[q];
        atomicAdd(ap + q*4 + 0, v.x);
        atomicAdd(ap + q*4 + 1, v.y);
        atomicAdd(ap + q*4 + 2, v.z);
        atomicAdd(ap + q*4 + 3, v.w);
    }
}
__global__ void k_post(const float* __restrict__ acc, const float* __restrict__ disq,
                       const float* __restrict__ b, float* __restrict__ hout) {
    __shared__ float bs[H];
    if (threadIdx.x < H) bs[threadIdx.x] = b[threadIdx.x];
    __syncthreads();
    int i = blockIdx.x * blockDim.x + threadIdx.x;
    if (i >= NN) return;
    float d = disq[i];
    const float4* ap = (const float4*)(acc + (size_t)i * H);
    float4* hp = (float4*)(hout + (size_t)i * H);
#pragma unroll
    for (int q = 0; q < 4; ++q) {
        float4 v = ap[q];
        float4 r;
        r.x = fmaxf(v.x * d + bs[q*4+0], 0.f);
        r.y = fmaxf(v.y * d + bs[q*4+1], 0.f);
        r.z = fmaxf(v.z * d + bs[q*4+2], 0.f);
        r.w = fmaxf(v.w * d + bs[q*4+3], 0.f);
        hp[q] = r;
    }
}

extern "C" void kernel_launch(void* const* d_in, const int* in_sizes, int n_in,
                              void* d_out, int out_size, void* d_ws, size_t ws_size,
                              hipStream_t stream) {
    const float* x   = (const float*)d_in[0];
    const float* W1  = (const float*)d_in[1];
    const float* b1  = (const float*)d_in[2];
    const float* W2  = (const float*)d_in[3];
    const float* b2  = (const float*)d_in[4];
    const float* Wf1 = (const float*)d_in[5];
    const float* bf1 = (const float*)d_in[6];
    const float* Wf2 = (const float*)d_in[7];
    const float* bf2 = (const float*)d_in[8];
    const int*   ei    = (const int*)d_in[9];
    const int*   batch = (const int*)d_in[10];
    const int* src = ei;        // edge_index row 0
    const int* dst = ei + NE;   // edge_index row 1
    float* out = (float*)d_out;

    const int BT  = 256;
    const int gbN = (NN + BT - 1) / BT;               // 586
    const int gbE = (NE + BT - 1) / BT;               // 18750 (fallback)
    const int NPB = BT / H;                           // 16
    const int gbG = (NN + NPB - 1) / NPB;             // 9375 gather blocks

    // ---- workspace layout (4-byte words; region starts 16B-aligned) ----
    // mat[512*512] | tot[512] | base[513]pad | ed[NE] | csr[NE] | rs[NN+1]pad |
    // disq[NN] | z0[NN*4 bf16 = 300000 words] | ybf[NN*H bf16] | bufB[NN*H f32] | g[NG*H]
    size_t need = ((size_t)14071368) * 4;   // ~56.3 MB
    if (ws_size >= need) {
        int*      mat  = (int*)d_ws;                   // 262144
        int*      tot  = mat + 262144;                 // 512
        int*      base = mat + 262656;                 // 513 (pad to 263172)
        unsigned* ed   = (unsigned*)(mat + 263172);    // NE
        int*      csr  = mat + 5063172;                // NE
        int*      rs   = mat + 9863172;                // NN+1 (pad to 10013176)
        float*    disq = (float*)(mat + 10013176);     // NN
        unsigned short* z0  = (unsigned short*)(mat + 10163176); // NN*4 bf16
        unsigned short* ybf = (unsigned short*)(mat + 10463176); // NN*H bf16
        float*    bufB = (float*)(mat + 11663176);     // NN*H
        float*    g    = (float*)(mat + 14063176);     // NG*H

        // graph bucketing (mat-driven) -> CSR + disq + z0
        k_hist2<<<NBLK, 512, 0, stream>>>(dst, mat);
        k_scanb<<<NB,   NBLK, 0, stream>>>(mat, tot);
        k_scant<<<1,    NB,  0, stream>>>(tot, base);
        k_part2<<<NBLK, 512, 0, stream>>>(src, dst, mat, tot, base, ed);
        k_csr2 <<<NB,   512, 0, stream>>>(ed, base, x, rs, csr, disq, z0);

        // conv1+hw2 fused: gather z0 (L2-resident), emit y2 bf16 directly
        k_gconv12<<<gbN, 256, 0, stream>>>(rs, csr, z0, disq, W1, b1, W2, ybf);
        // conv2
        k_gather<<<gbG, 256, 0, stream>>>(rs, csr, ybf, disq, b2, bufB);      // h2
        // pool + MLP
        k_pool_blk<<<NG, 256, 0, stream>>>(bufB, batch, g);
        k_mlp<<<1, 512, 0, stream>>>(g, Wf1, bf1, Wf2, bf2, out);
    } else {
        // fallback: baseline atomic-scatter path (~20 MB ws, f32)
        float* disq = (float*)d_ws;
        float* bufA = disq + NN;
        float* bufB = bufA + (size_t)NN * H;
        float* g    = bufB + (size_t)NN * H;

        k_deg_init<<<gbN, BT, 0, stream>>>(disq);
        k_deg_edges<<<gbE, BT, 0, stream>>>(dst, disq);
        k_disq<<<gbN, BT, 0, stream>>>(disq);

        k_xw1f<<<gbN, BT, 0, stream>>>(x, W1, disq, bufA);
        hipMemcpyAsync(bufB, bufA, (size_t)NN * H * sizeof(float),
                       hipMemcpyDeviceToDevice, stream);
        k_scatter<<<gbE, BT, 0, stream>>>(src, dst, bufA, bufB);
        k_post<<<gbN, BT, 0, stream>>>(bufB, disq, b1, bufA);

        k_hw2f<<<gbN, BT, 0, stream>>>(bufA, W2, disq, bufB);
        hipMemcpyAsync(bufA, bufB, (size_t)NN * H * sizeof(float),
                       hipMemcpyDeviceToDevice, stream);
        k_scatter<<<gbE, BT, 0, stream>>>(src, dst, bufB, bufA);
        k_post<<<gbN, BT, 0, stream>>>(bufA, disq, b2, bufB);

        k_pool_blk<<<NG, BT, 0, stream>>>(bufB, batch, g);
        k_mlp<<<1, 512, 0, stream>>>(g, Wf1, bf1, Wf2, bf2, out);
    }
}

// Round 22
// 160.886 us; speedup vs baseline: 5.4288x; 1.0656x over previous
//
#include <hip/hip_runtime.h>

constexpr int NN = 150000;   // nodes
constexpr int NE = 4800000;  // edges
constexpr int NG = 512;      // graphs
constexpr int H  = 16;       // hidden
constexpr int NB   = 512;    // coarse dst-buckets
constexpr int NPBK = 293;    // nodes per bucket (512*293 = 150016 >= NN)
constexpr int NBLK = 512;    // streaming blocks for hist/part
constexpr int CHUNK = NE / NBLK;   // 9375 edges per block (exact)
constexpr int CAP = 11776;   // k_csr2 LDS staging capacity (mean 9375, +24 sigma)

__device__ inline unsigned short f2bf(float f) {
    union { float f; unsigned u; } v; v.f = f;
    unsigned r = v.u + 0x7FFFu + ((v.u >> 16) & 1u);   // RNE
    return (unsigned short)(r >> 16);
}
__device__ inline float bf2f(unsigned short s) {
    union { unsigned u; float f; } v; v.u = ((unsigned)s) << 16;
    return v.f;
}

// ---------- phase A: per-block LDS histogram -> mat[b][bucket] ----------
__global__ void k_hist2(const int* __restrict__ dst, int* __restrict__ mat) {
    __shared__ int cnt[NB];
    cnt[threadIdx.x] = 0;
    __syncthreads();
    int b = blockIdx.x;
    int e0 = b * CHUNK, e1 = e0 + CHUNK;
    for (int e = e0 + (int)threadIdx.x; e < e1; e += 512)
        atomicAdd(&cnt[dst[e] / NPBK], 1);
    __syncthreads();
    mat[b * NB + threadIdx.x] = cnt[threadIdx.x];
}

// ---------- column scan: mat[:,j] -> exclusive prefix (in place), totals ----------
__global__ void k_scanb(int* __restrict__ mat, int* __restrict__ tot) {
    __shared__ int tmp[NBLK];
    int j = blockIdx.x, t = threadIdx.x;
    int v = mat[t * NB + j];
    tmp[t] = v;
    __syncthreads();
    for (int off = 1; off < NBLK; off <<= 1) {
        int a = (t >= off) ? tmp[t - off] : 0;
        __syncthreads();
        tmp[t] += a;
        __syncthreads();
    }
    mat[t * NB + j] = tmp[t] - v;               // exclusive within column
    if (t == NBLK - 1) tot[j] = tmp[t];
}

// ---------- bucket base scan (exclusive over NB buckets) ----------
__global__ void k_scant(const int* __restrict__ tot, int* __restrict__ base) {
    __shared__ int tmp[NB];
    int t = threadIdx.x;
    int v = tot[t];
    tmp[t] = v;
    __syncthreads();
    for (int off = 1; off < NB; off <<= 1) {
        int a = (t >= off) ? tmp[t - off] : 0;
        __syncthreads();
        tmp[t] += a;
        __syncthreads();
    }
    base[t] = tmp[t] - v;
    if (t == 0) base[NB] = NE;
}

// ---------- phase B: LDS-staged partition (counts from mat), coalesced writeout ----------
__global__ void k_part2(const int* __restrict__ src, const int* __restrict__ dst,
                        const int* __restrict__ mat, const int* __restrict__ tot,
                        const int* __restrict__ base, unsigned* __restrict__ ed) {
    __shared__ int off[NB];          // exclusive local offsets
    __shared__ int gsnap[NB];        // global run base per bucket
    __shared__ int lcur[NB];         // local scatter cursors
    __shared__ unsigned stg[CHUNK];  // 37.5 KB staging
    int b = blockIdx.x, t = threadIdx.x;
    int e0 = b * CHUNK, e1 = e0 + CHUNK;
    int exg = mat[b * NB + t];                       // col-exclusive (blocks < b)
    int nxt = (b + 1 < NBLK) ? mat[(b + 1) * NB + t] : tot[t];
    int v = nxt - exg;                               // my count for bucket t
    gsnap[t] = base[t] + exg;
    off[t] = v;
    __syncthreads();
    for (int o = 1; o < NB; o <<= 1) {
        int a = (t >= o) ? off[t - o] : 0;
        __syncthreads();
        off[t] += a;
        __syncthreads();
    }
    int excl = off[t] - v;
    __syncthreads();
    off[t]  = excl;
    lcur[t] = excl;
    __syncthreads();
    // scatter into LDS staging (bucket-grouped)
    for (int e = e0 + t; e < e1; e += 512) {
        int d = dst[e];
        int bq = d / NPBK;
        int p = atomicAdd(&lcur[bq], 1);
        stg[p] = (unsigned)src[e] | ((unsigned)(d - bq * NPBK) << 18);
    }
    __syncthreads();
    // writeout: one wave per bucket run, coalesced
    int wave = t >> 6, lane = t & 63;
    for (int bb = wave; bb < NB; bb += 8) {
        int o = off[bb];
        int c = lcur[bb] - o;
        int gb = gsnap[bb];
        for (int k = lane; k < c; k += 64)
            ed[gb + k] = stg[o + k];
    }
}

// ---------- phase B2: counting sort -> CSR + disq + z0 = bf16(x*disq) ----------
__global__ void k_csr2(const unsigned* __restrict__ ed, const int* __restrict__ base,
                       const float* __restrict__ x,
                       int* __restrict__ rs, int* __restrict__ csr,
                       float* __restrict__ disq, unsigned short* __restrict__ z0) {
    __shared__ int cnt[NB];
    __shared__ int scn[NB];
    __shared__ int stg[CAP];         // 46 KB staging
    int j = blockIdx.x, t = threadIdx.x;
    cnt[t] = 0;
    __syncthreads();
    int e0 = base[j], e1 = base[j + 1];
    int m = e1 - e0;
    for (int e = e0 + t; e < e1; e += 512)
        atomicAdd(&cnt[ed[e] >> 18], 1);
    __syncthreads();
    int v = cnt[t];
    scn[t] = v;
    __syncthreads();
    for (int off = 1; off < NB; off <<= 1) {
        int a = (t >= off) ? scn[t - off] : 0;
        __syncthreads();
        scn[t] += a;
        __syncthreads();
    }
    int excl = scn[t] - v;
    int n0 = j * NPBK;
    int n = n0 + t;
    if (t < NPBK && n < NN) {
        rs[n] = e0 + excl;
        float dq = rsqrtf((float)(v + 1));       // +1 self-loop
        disq[n] = dq;
        float4 xv = ((const float4*)x)[n];
        unsigned lo = (unsigned)f2bf(xv.x * dq) | ((unsigned)f2bf(xv.y * dq) << 16);
        unsigned hi = (unsigned)f2bf(xv.z * dq) | ((unsigned)f2bf(xv.w * dq) << 16);
        ((uint2*)(z0 + (size_t)n * 4))[0] = make_uint2(lo, hi);
    }
    cnt[t] = excl;                               // cursors
    __syncthreads();
    if (m <= CAP) {
        for (int e = e0 + t; e < e1; e += 512) {
            unsigned ee = ed[e];
            int p = atomicAdd(&cnt[ee >> 18], 1);
            stg[p] = (int)(ee & 0x3FFFFu);
        }
        __syncthreads();
        for (int k = t; k < m; k += 512) csr[e0 + k] = stg[k];   // coalesced
    } else {
        for (int e = e0 + t; e < e1; e += 512) {
            unsigned ee = ed[e];
            int p = atomicAdd(&cnt[ee >> 18], 1);
            csr[e0 + p] = (int)(ee & 0x3FFFFu);
        }
    }
    if (j == 0 && t == 0) rs[NN] = NE;
}

// ---------- fused conv1+W2: gather z0 (L2-resident), h1 in regs, emit y2 bf16 ----------
__global__ void k_gconv12(const int* __restrict__ rs, const int* __restrict__ csr,
                          const unsigned short* __restrict__ z0, const float* __restrict__ disq,
                          const float* __restrict__ W1, const float* __restrict__ b1,
                          const float* __restrict__ W2, unsigned short* __restrict__ yout) {
    __shared__ float w[4 * H];
    __shared__ float bs[H];
    __shared__ float w2[H * H];
    if (threadIdx.x < 4 * H) w[threadIdx.x] = W1[threadIdx.x];
    if (threadIdx.x < H) bs[threadIdx.x] = b1[threadIdx.x];
    if (threadIdx.x < H * H) w2[threadIdx.x] = W2[threadIdx.x];
    __syncthreads();
    int n = blockIdx.x * blockDim.x + threadIdx.x;
    if (n >= NN) return;
    int s0 = rs[n], s1 = rs[n + 1];
    uint2 zs = ((const uint2*)(z0 + (size_t)n * 4))[0];      // self-loop
    float a0 = bf2f((unsigned short)(zs.x & 0xFFFF));
    float a1 = bf2f((unsigned short)(zs.x >> 16));
    float a2 = bf2f((unsigned short)(zs.y & 0xFFFF));
    float a3 = bf2f((unsigned short)(zs.y >> 16));
    int k = s0;
    for (; k + 8 <= s1; k += 8) {
        int i0 = csr[k+0], i1 = csr[k+1], i2 = csr[k+2], i3 = csr[k+3];
        int i4 = csr[k+4], i5 = csr[k+5], i6 = csr[k+6], i7 = csr[k+7];
        uint2 v0 = ((const uint2*)(z0 + (size_t)i0 * 4))[0];
        uint2 v1 = ((const uint2*)(z0 + (size_t)i1 * 4))[0];
        uint2 v2 = ((const uint2*)(z0 + (size_t)i2 * 4))[0];
        uint2 v3 = ((const uint2*)(z0 + (size_t)i3 * 4))[0];
        uint2 v4 = ((const uint2*)(z0 + (size_t)i4 * 4))[0];
        uint2 v5 = ((const uint2*)(z0 + (size_t)i5 * 4))[0];
        uint2 v6 = ((const uint2*)(z0 + (size_t)i6 * 4))[0];
        uint2 v7 = ((const uint2*)(z0 + (size_t)i7 * 4))[0];
#define ACC4(vv) { \
        a0 += bf2f((unsigned short)(vv.x & 0xFFFF)); \
        a1 += bf2f((unsigned short)(vv.x >> 16)); \
        a2 += bf2f((unsigned short)(vv.y & 0xFFFF)); \
        a3 += bf2f((unsigned short)(vv.y >> 16)); }
        ACC4(v0) ACC4(v1) ACC4(v2) ACC4(v3) ACC4(v4) ACC4(v5) ACC4(v6) ACC4(v7)
    }
    for (; k < s1; ++k) {
        uint2 v = ((const uint2*)(z0 + (size_t)csr[k] * 4))[0];
        ACC4(v)
    }
#undef ACC4
    float d = disq[n];
    a0 *= d; a1 *= d; a2 *= d; a3 *= d;
    float o[H];
#pragma unroll
    for (int h = 0; h < H; ++h)
        o[h] = fmaxf(a0 * w[0*H + h] + a1 * w[1*H + h] +
                     a2 * w[2*H + h] + a3 * w[3*H + h] + bs[h], 0.f);
    float o2[H];
#pragma unroll
    for (int h = 0; h < H; ++h) {
        float s = 0.f;
#pragma unroll
        for (int kk = 0; kk < H; ++kk) s += o[kk] * w2[kk*H + h];
        o2[h] = s * d;
    }
    unsigned pk[8];
#pragma unroll
    for (int q = 0; q < 8; ++q)
        pk[q] = (unsigned)f2bf(o2[2*q]) | ((unsigned)f2bf(o2[2*q+1]) << 16);
    uint4* yp = (uint4*)(yout + (size_t)n * H);
    yp[0] = make_uint4(pk[0], pk[1], pk[2], pk[3]);
    yp[1] = make_uint4(pk[4], pk[5], pk[6], pk[7]);
}

// ---------- conv2 gather + fused pool: h2 stays in registers/LDS, only g is written ----------
// h2[n] = relu(disq*(y[n]+sum y[csr]) + b);  g[batch[n]] += h2[n]  (run-length + atomic)
__global__ void k_gather_pool(const int* __restrict__ rs, const int* __restrict__ csr,
                              const unsigned short* __restrict__ y,
                              const float* __restrict__ b, const int* __restrict__ batch,
                              float* __restrict__ g) {
    __shared__ float red[16][H + 1];
    __shared__ int   bid[16];
    int n    = blockIdx.x * 16 + (threadIdx.x >> 4);
    int lane = threadIdx.x & 15;
    int grp  = threadIdx.x >> 4;
    float hval = 0.f;
    if (n < NN) {
        int s0 = rs[n], s1 = rs[n + 1];
        float dq = rsqrtf((float)(s1 - s0 + 1));     // bit-identical to stored disq
        float acc = bf2f(y[(size_t)n * H + lane]);   // self-loop term
        int k = s0;
        for (; k + 8 <= s1; k += 8) {
            int sa = csr[k+0], sb = csr[k+1], sc = csr[k+2], sd = csr[k+3];
            int se = csr[k+4], sf = csr[k+5], sg = csr[k+6], sh = csr[k+7];
            float v0 = bf2f(y[(size_t)sa * H + lane]);
            float v1 = bf2f(y[(size_t)sb * H + lane]);
            float v2 = bf2f(y[(size_t)sc * H + lane]);
            float v3 = bf2f(y[(size_t)sd * H + lane]);
            float v4 = bf2f(y[(size_t)se * H + lane]);
            float v5 = bf2f(y[(size_t)sf * H + lane]);
            float v6 = bf2f(y[(size_t)sg * H + lane]);
            float v7 = bf2f(y[(size_t)sh * H + lane]);
            acc += ((v0 + v1) + (v2 + v3)) + ((v4 + v5) + (v6 + v7));
        }
        for (; k < s1; ++k) acc += bf2f(y[(size_t)csr[k] * H + lane]);
        hval = fmaxf(fmaf(acc, dq, b[lane]), 0.f);
        if (lane == 0) bid[grp] = batch[n];
    } else if (lane == 0) {
        bid[grp] = -1;
    }
    red[grp][lane] = hval;
    __syncthreads();
    if (grp == 0) {
        int cur = bid[0];
        float acc = red[0][lane];
        for (int r = 1; r < 16; ++r) {
            int bb = bid[r];
            if (bb != cur) {
                if (cur >= 0) atomicAdd(&g[(size_t)cur * H + lane], acc);
                acc = 0.f;
                cur = bb;
            }
            acc += red[r][lane];
        }
        if (cur >= 0) atomicAdd(&g[(size_t)cur * H + lane], acc);
    }
}

// ---------- final MLP ----------
__global__ void k_mlp(const float* __restrict__ g, const float* __restrict__ Wf1,
                      const float* __restrict__ bf1, const float* __restrict__ Wf2,
                      const float* __restrict__ bf2, float* __restrict__ out) {
    __shared__ float w1[H * H];
    __shared__ float b1s[H];
    __shared__ float w2[H];
    __shared__ float b2s;
    if (threadIdx.x < H * H) w1[threadIdx.x] = Wf1[threadIdx.x];
    if (threadIdx.x < H) { b1s[threadIdx.x] = bf1[threadIdx.x]; w2[threadIdx.x] = Wf2[threadIdx.x]; }
    if (threadIdx.x == 0) b2s = bf2[0];
    __syncthreads();
    int i = blockIdx.x * blockDim.x + threadIdx.x;
    if (i >= NG) return;
    float gv[H];
    const float4* gp = (const float4*)(g + (size_t)i * H);
#pragma unroll
    for (int q = 0; q < 4; ++q) ((float4*)gv)[q] = gp[q];
    float s2 = 0.f;
#pragma unroll
    for (int h = 0; h < H; ++h) {
        float t = b1s[h];
#pragma unroll
        for (int k = 0; k < H; ++k) t += gv[k] * w1[k*H + h];
        s2 += fmaxf(t, 0.f) * w2[h];
    }
    out[i] = s2 + b2s;
}

// ================= fallback (baseline atomic path, f32) =================
__global__ void k_deg_init(float* __restrict__ deg) {
    int i = blockIdx.x * blockDim.x + threadIdx.x;
    if (i < NN) deg[i] = 1.0f;
}
__global__ void k_deg_edges(const int* __restrict__ dst, float* __restrict__ deg) {
    int i = blockIdx.x * blockDim.x + threadIdx.x;
    if (i < NE) atomicAdd(&deg[dst[i]], 1.0f);
}
__global__ void k_disq(float* __restrict__ deg) {
    int i = blockIdx.x * blockDim.x + threadIdx.x;
    if (i < NN) deg[i] = rsqrtf(deg[i]);
}
__global__ void k_xw1f(const float* __restrict__ x, const float* __restrict__ W1,
                       const float* __restrict__ disq, float* __restrict__ y) {
    __shared__ float w[4 * H];
    if (threadIdx.x < 4 * H) w[threadIdx.x] = W1[threadIdx.x];
    __syncthreads();
    int i = blockIdx.x * blockDim.x + threadIdx.x;
    if (i >= NN) return;
    float4 xv = ((const float4*)x)[i];
    float d = disq[i];
    float o[H];
#pragma unroll
    for (int h = 0; h < H; ++h)
        o[h] = (xv.x * w[0*H + h] + xv.y * w[1*H + h] +
                xv.z * w[2*H + h] + xv.w * w[3*H + h]) * d;
    float4* yp = (float4*)(y + (size_t)i * H);
#pragma unroll
    for (int q = 0; q < 4; ++q) yp[q] = ((float4*)o)[q];
}
__global__ void k_hw2f(const float* __restrict__ hin, const float* __restrict__ W2,
                       const float* __restrict__ disq, float* __restrict__ yout) {
    __shared__ float w[H * H];
    if (threadIdx.x < H * H) w[threadIdx.x] = W2[threadIdx.x];
    __syncthreads();
    int i = blockIdx.x * blockDim.x + threadIdx.x;
    if (i >= NN) return;
    float hv[H];
    const float4* hp = (const float4*)(hin + (size_t)i * H);
#pragma unroll
    for (int q = 0; q < 4; ++q) ((float4*)hv)[q] = hp[q];
    float d = disq[i];
    float o[H];
#pragma unroll
    for (int h = 0; h < H; ++h) {
        float s = 0.f;
#pragma unroll
        for (int k = 0; k < H; ++k) s += hv[k] * w[k*H + h];
        o[h] = s * d;
    }
    float4* yp = (float4*)(yout + (size_t)i * H);
#pragma unroll
    for (int q = 0; q < 4; ++q) yp[q] = ((float4*)o)[q];
}
__global__ void k_scatter(const int* __restrict__ src, const int* __restrict__ dst,
                          const float* __restrict__ y, float* __restrict__ acc) {
    int i = blockIdx.x * blockDim.x + threadIdx.x;
    if (i >= NE) return;
    int s = src[i], d = dst[i];
    const float4* yp = (const float4*)(y + (size_t)s * H);
    float* ap = acc + (size_t)d * H;
#pragma unroll
    for (int q = 0; q < 4; ++q) {
        float4 v = yp[q];
        atomicAdd(ap + q*4 + 0, v.x);
        atomicAdd(ap + q*4 + 1, v.y);
        atomicAdd(ap + q*4 + 2, v.z);
        atomicAdd(ap + q*4 + 3, v.w);
    }
}
__global__ void k_post(const float* __restrict__ acc, const float* __restrict__ disq,
                       const float* __restrict__ b, float* __restrict__ hout) {
    __shared__ float bs[H];
    if (threadIdx.x < H) bs[threadIdx.x] = b[threadIdx.x];
    __syncthreads();
    int i = blockIdx.x * blockDim.x + threadIdx.x;
    if (i >= NN) return;
    float d = disq[i];
    const float4* ap = (const float4*)(acc + (size_t)i * H);
    float4* hp = (float4*)(hout + (size_t)i * H);
#pragma unroll
    for (int q = 0; q < 4; ++q) {
        float4 v = ap[q];
        float4 r;
        r.x = fmaxf(v.x * d + bs[q*4+0], 0.f);
        r.y = fmaxf(v.y * d + bs[q*4+1], 0.f);
        r.z = fmaxf(v.z * d + bs[q*4+2], 0.f);
        r.w = fmaxf(v.w * d + bs[q*4+3], 0.f);
        hp[q] = r;
    }
}
__global__ void k_pool_blk(const float* __restrict__ h, const int* __restrict__ batch,
                           float* __restrict__ gout) {
    __shared__ float red[16][H + 1];
    int g    = blockIdx.x;
    int lane = threadIdx.x & 15;
    int grp  = threadIdx.x >> 4;
    int lo = 0, hi = NN;
    while (lo < hi) { int m = (lo + hi) >> 1; if (batch[m] < g) lo = m + 1; else hi = m; }
    int start = lo;
    hi = NN;
    while (lo < hi) { int m = (lo + hi) >> 1; if (batch[m] < g + 1) lo = m + 1; else hi = m; }
    int end = lo;
    float acc = 0.f;
    for (int i = start + grp; i < end; i += 16)
        acc += h[(size_t)i * H + lane];
    red[grp][lane] = acc;
    __syncthreads();
    if (grp < 8) red[grp][lane] += red[grp + 8][lane];
    __syncthreads();
    if (grp < 4) red[grp][lane] += red[grp + 4][lane];
    __syncthreads();
    if (grp < 2) red[grp][lane] += red[grp + 2][lane];
    __syncthreads();
    if (grp == 0)
        gout[(size_t)g * H + lane] = red[0][lane] + red[1][lane];
}

extern "C" void kernel_launch(void* const* d_in, const int* in_sizes, int n_in,
                              void* d_out, int out_size, void* d_ws, size_t ws_size,
                              hipStream_t stream) {
    const float* x   = (const float*)d_in[0];
    const float* W1  = (const float*)d_in[1];
    const float* b1  = (const float*)d_in[2];
    const float* W2  = (const float*)d_in[3];
    const float* b2  = (const float*)d_in[4];
    const float* Wf1 = (const float*)d_in[5];
    const float* bf1 = (const float*)d_in[6];
    const float* Wf2 = (const float*)d_in[7];
    const float* bf2 = (const float*)d_in[8];
    const int*   ei    = (const int*)d_in[9];
    const int*   batch = (const int*)d_in[10];
    const int* src = ei;        // edge_index row 0
    const int* dst = ei + NE;   // edge_index row 1
    float* out = (float*)d_out;

    const int BT  = 256;
    const int gbN = (NN + BT - 1) / BT;               // 586
    const int gbE = (NE + BT - 1) / BT;               // 18750 (fallback)
    const int NPB = BT / H;                           // 16
    const int gbG = (NN + NPB - 1) / NPB;             // 9375 gather blocks

    // ---- workspace layout (4-byte words; region starts 16B-aligned) ----
    // mat[512*512] | tot[512] | base[513]pad | ed[NE] | csr[NE] | rs[NN+1]pad |
    // disq[NN] | z0[NN*4 bf16] | ybf[NN*H bf16] | bufB[NN*H f32 (fallback only)] | g[NG*H]
    size_t need = ((size_t)14071368) * 4;   // ~56.3 MB
    if (ws_size >= need) {
        int*      mat  = (int*)d_ws;                   // 262144
        int*      tot  = mat + 262144;                 // 512
        int*      base = mat + 262656;                 // 513 (pad to 263172)
        unsigned* ed   = (unsigned*)(mat + 263172);    // NE
        int*      csr  = mat + 5063172;                // NE
        int*      rs   = mat + 9863172;                // NN+1 (pad to 10013176)
        float*    disq = (float*)(mat + 10013176);     // NN
        unsigned short* z0  = (unsigned short*)(mat + 10163176); // NN*4 bf16
        unsigned short* ybf = (unsigned short*)(mat + 10463176); // NN*H bf16
        float*    g    = (float*)(mat + 14063176);     // NG*H

        // graph bucketing (mat-driven) -> CSR + disq + z0
        k_hist2<<<NBLK, 512, 0, stream>>>(dst, mat);
        k_scanb<<<NB,   NBLK, 0, stream>>>(mat, tot);
        k_scant<<<1,    NB,  0, stream>>>(tot, base);
        k_part2<<<NBLK, 512, 0, stream>>>(src, dst, mat, tot, base, ed);
        k_csr2 <<<NB,   512, 0, stream>>>(ed, base, x, rs, csr, disq, z0);

        // conv1+hw2 fused: gather z0 (L2-resident), emit y2 bf16 directly
        k_gconv12<<<gbN, 256, 0, stream>>>(rs, csr, z0, disq, W1, b1, W2, ybf);
        // conv2 gather + fused pool (h2 never materialized)
        hipMemsetAsync(g, 0, (size_t)NG * H * sizeof(float), stream);
        k_gather_pool<<<gbG, 256, 0, stream>>>(rs, csr, ybf, b2, batch, g);
        // MLP
        k_mlp<<<1, 512, 0, stream>>>(g, Wf1, bf1, Wf2, bf2, out);
    } else {
        // fallback: baseline atomic-scatter path (~20 MB ws, f32)
        float* disq = (float*)d_ws;
        float* bufA = disq + NN;
        float* bufB = bufA + (size_t)NN * H;
        float* g    = bufB + (size_t)NN * H;

        k_deg_init<<<gbN, BT, 0, stream>>>(disq);
        k_deg_edges<<<gbE, BT, 0, stream>>>(dst, disq);
        k_disq<<<gbN, BT, 0, stream>>>(disq);

        k_xw1f<<<gbN, BT, 0, stream>>>(x, W1, disq, bufA);
        hipMemcpyAsync(bufB, bufA, (size_t)NN * H * sizeof(float),
                       hipMemcpyDeviceToDevice, stream);
        k_scatter<<<gbE, BT, 0, stream>>>(src, dst, bufA, bufB);
        k_post<<<gbN, BT, 0, stream>>>(bufB, disq, b1, bufA);

        k_hw2f<<<gbN, BT, 0, stream>>>(bufA, W2, disq, bufB);
        hipMemcpyAsync(bufA, bufB, (size_t)NN * H * sizeof(float),
                       hipMemcpyDeviceToDevice, stream);
        k_scatter<<<gbE, BT, 0, stream>>>(src, dst, bufB, bufA);
        k_post<<<gbN, BT, 0, stream>>>(bufA, disq, b2, bufB);

        k_pool_blk<<<NG, BT, 0, stream>>>(bufB, batch, g);
        k_mlp<<<1, 512, 0, stream>>>(g, Wf1, bf1, Wf2, bf2, out);
    }
}

// Round 23
// 156.139 us; speedup vs baseline: 5.5939x; 1.0304x over previous
//
#include <hip/hip_runtime.h>

constexpr int NN = 150000;   // nodes
constexpr int NE = 4800000;  // edges
constexpr int NG = 512;      // graphs
constexpr int H  = 16;       // hidden
constexpr int NB   = 512;    // coarse dst-buckets
constexpr int NPBK = 293;    // nodes per bucket (512*293 = 150016 >= NN)
constexpr int NBLK = 512;    // streaming blocks for hist/part
constexpr int CHUNK = NE / NBLK;   // 9375 edges per block (exact)
constexpr int CAP = 11776;   // k_csr2 LDS staging capacity (mean 9375, +24 sigma)
constexpr int EPT = 23;      // edges per thread register stage (CAP/512)

__device__ inline unsigned short f2bf(float f) {
    union { float f; unsigned u; } v; v.f = f;
    unsigned r = v.u + 0x7FFFu + ((v.u >> 16) & 1u);   // RNE
    return (unsigned short)(r >> 16);
}
__device__ inline float bf2f(unsigned short s) {
    union { unsigned u; float f; } v; v.u = ((unsigned)s) << 16;
    return v.f;
}

// ---------- phase A: per-block LDS histogram -> mat[b][bucket] ----------
__global__ void k_hist2(const int* __restrict__ dst, int* __restrict__ mat) {
    __shared__ int cnt[NB];
    cnt[threadIdx.x] = 0;
    __syncthreads();
    int b = blockIdx.x;
    int e0 = b * CHUNK, e1 = e0 + CHUNK;
    for (int e = e0 + (int)threadIdx.x; e < e1; e += 512)
        atomicAdd(&cnt[dst[e] / NPBK], 1);
    __syncthreads();
    mat[b * NB + threadIdx.x] = cnt[threadIdx.x];
}

// ---------- column scan: mat[:,j] -> exclusive prefix (in place), totals ----------
__global__ void k_scanb(int* __restrict__ mat, int* __restrict__ tot) {
    __shared__ int tmp[NBLK];
    int j = blockIdx.x, t = threadIdx.x;
    int v = mat[t * NB + j];
    tmp[t] = v;
    __syncthreads();
    for (int off = 1; off < NBLK; off <<= 1) {
        int a = (t >= off) ? tmp[t - off] : 0;
        __syncthreads();
        tmp[t] += a;
        __syncthreads();
    }
    mat[t * NB + j] = tmp[t] - v;               // exclusive within column
    if (t == NBLK - 1) tot[j] = tmp[t];
}

// ---------- bucket base scan (exclusive over NB buckets) ----------
__global__ void k_scant(const int* __restrict__ tot, int* __restrict__ base) {
    __shared__ int tmp[NB];
    int t = threadIdx.x;
    int v = tot[t];
    tmp[t] = v;
    __syncthreads();
    for (int off = 1; off < NB; off <<= 1) {
        int a = (t >= off) ? tmp[t - off] : 0;
        __syncthreads();
        tmp[t] += a;
        __syncthreads();
    }
    base[t] = tmp[t] - v;
    if (t == 0) base[NB] = NE;
}

// ---------- phase B: LDS-staged partition (counts from mat), coalesced writeout ----------
__global__ void k_part2(const int* __restrict__ src, const int* __restrict__ dst,
                        const int* __restrict__ mat, const int* __restrict__ tot,
                        const int* __restrict__ base, unsigned* __restrict__ ed) {
    __shared__ int off[NB];          // exclusive local offsets
    __shared__ int gsnap[NB];        // global run base per bucket
    __shared__ int lcur[NB];         // local scatter cursors
    __shared__ unsigned stg[CHUNK];  // 37.5 KB staging
    int b = blockIdx.x, t = threadIdx.x;
    int e0 = b * CHUNK, e1 = e0 + CHUNK;
    int exg = mat[b * NB + t];                       // col-exclusive (blocks < b)
    int nxt = (b + 1 < NBLK) ? mat[(b + 1) * NB + t] : tot[t];
    int v = nxt - exg;                               // my count for bucket t
    gsnap[t] = base[t] + exg;
    off[t] = v;
    __syncthreads();
    for (int o = 1; o < NB; o <<= 1) {
        int a = (t >= o) ? off[t - o] : 0;
        __syncthreads();
        off[t] += a;
        __syncthreads();
    }
    int excl = off[t] - v;
    __syncthreads();
    off[t]  = excl;
    lcur[t] = excl;
    __syncthreads();
    // scatter into LDS staging (bucket-grouped)
    for (int e = e0 + t; e < e1; e += 512) {
        int d = dst[e];
        int bq = d / NPBK;
        int p = atomicAdd(&lcur[bq], 1);
        stg[p] = (unsigned)src[e] | ((unsigned)(d - bq * NPBK) << 18);
    }
    __syncthreads();
    // writeout: one wave per bucket run, coalesced
    int wave = t >> 6, lane = t & 63;
    for (int bb = wave; bb < NB; bb += 8) {
        int o = off[bb];
        int c = lcur[bb] - o;
        int gb = gsnap[bb];
        for (int k = lane; k < c; k += 64)
            ed[gb + k] = stg[o + k];
    }
}

// ---------- phase B2: counting sort -> CSR + disq + z0; ed register-staged ----------
__global__ void k_csr2(const unsigned* __restrict__ ed, const int* __restrict__ base,
                       const float* __restrict__ x,
                       int* __restrict__ rs, int* __restrict__ csr,
                       float* __restrict__ disq, unsigned short* __restrict__ z0) {
    __shared__ int cnt[NB];
    __shared__ int scn[NB];
    __shared__ int stg[CAP];         // 46 KB staging
    int j = blockIdx.x, t = threadIdx.x;
    cnt[t] = 0;
    __syncthreads();
    int e0 = base[j], e1 = base[j + 1];
    int m = e1 - e0;
    bool fits = (m <= CAP);
    unsigned ev[EPT];                // register-staged edges (static indexing only)
    if (fits) {
#pragma unroll
        for (int q = 0; q < EPT; ++q) {
            int e = e0 + q * 512 + t;
            ev[q] = (e < e1) ? ed[e] : 0xFFFFFFFFu;   // valid words < 2^27
        }
#pragma unroll
        for (int q = 0; q < EPT; ++q)
            if (ev[q] != 0xFFFFFFFFu) atomicAdd(&cnt[ev[q] >> 18], 1);
    } else {
        for (int e = e0 + t; e < e1; e += 512)
            atomicAdd(&cnt[ed[e] >> 18], 1);
    }
    __syncthreads();
    int v = cnt[t];
    scn[t] = v;
    __syncthreads();
    for (int off = 1; off < NB; off <<= 1) {
        int a = (t >= off) ? scn[t - off] : 0;
        __syncthreads();
        scn[t] += a;
        __syncthreads();
    }
    int excl = scn[t] - v;
    int n0 = j * NPBK;
    int n = n0 + t;
    if (t < NPBK && n < NN) {
        rs[n] = e0 + excl;
        float dq = rsqrtf((float)(v + 1));       // +1 self-loop
        disq[n] = dq;
        float4 xv = ((const float4*)x)[n];
        unsigned lo = (unsigned)f2bf(xv.x * dq) | ((unsigned)f2bf(xv.y * dq) << 16);
        unsigned hi = (unsigned)f2bf(xv.z * dq) | ((unsigned)f2bf(xv.w * dq) << 16);
        ((uint2*)(z0 + (size_t)n * 4))[0] = make_uint2(lo, hi);
    }
    cnt[t] = excl;                               // cursors
    __syncthreads();
    if (fits) {
#pragma unroll
        for (int q = 0; q < EPT; ++q) {
            unsigned ee = ev[q];
            if (ee != 0xFFFFFFFFu) {
                int p = atomicAdd(&cnt[ee >> 18], 1);
                stg[p] = (int)(ee & 0x3FFFFu);
            }
        }
        __syncthreads();
        for (int k = t; k < m; k += 512) csr[e0 + k] = stg[k];   // coalesced
    } else {
        for (int e = e0 + t; e < e1; e += 512) {
            unsigned ee = ed[e];
            int p = atomicAdd(&cnt[ee >> 18], 1);
            csr[e0 + p] = (int)(ee & 0x3FFFFu);
        }
    }
    if (j == 0 && t == 0) rs[NN] = NE;
}

// ---------- fused conv1+W2: gather z0 (L2-resident), h1 in regs, emit y2 bf16 ----------
__global__ void k_gconv12(const int* __restrict__ rs, const int* __restrict__ csr,
                          const unsigned short* __restrict__ z0, const float* __restrict__ disq,
                          const float* __restrict__ W1, const float* __restrict__ b1,
                          const float* __restrict__ W2, unsigned short* __restrict__ yout) {
    __shared__ float w[4 * H];
    __shared__ float bs[H];
    __shared__ float w2[H * H];
    if (threadIdx.x < 4 * H) w[threadIdx.x] = W1[threadIdx.x];
    if (threadIdx.x < H) bs[threadIdx.x] = b1[threadIdx.x];
    if (threadIdx.x < H * H) w2[threadIdx.x] = W2[threadIdx.x];
    __syncthreads();
    int n = blockIdx.x * blockDim.x + threadIdx.x;
    if (n >= NN) return;
    int s0 = rs[n], s1 = rs[n + 1];
    uint2 zs = ((const uint2*)(z0 + (size_t)n * 4))[0];      // self-loop
    float a0 = bf2f((unsigned short)(zs.x & 0xFFFF));
    float a1 = bf2f((unsigned short)(zs.x >> 16));
    float a2 = bf2f((unsigned short)(zs.y & 0xFFFF));
    float a3 = bf2f((unsigned short)(zs.y >> 16));
    int k = s0;
    for (; k + 8 <= s1; k += 8) {
        int i0 = csr[k+0], i1 = csr[k+1], i2 = csr[k+2], i3 = csr[k+3];
        int i4 = csr[k+4], i5 = csr[k+5], i6 = csr[k+6], i7 = csr[k+7];
        uint2 v0 = ((const uint2*)(z0 + (size_t)i0 * 4))[0];
        uint2 v1 = ((const uint2*)(z0 + (size_t)i1 * 4))[0];
        uint2 v2 = ((const uint2*)(z0 + (size_t)i2 * 4))[0];
        uint2 v3 = ((const uint2*)(z0 + (size_t)i3 * 4))[0];
        uint2 v4 = ((const uint2*)(z0 + (size_t)i4 * 4))[0];
        uint2 v5 = ((const uint2*)(z0 + (size_t)i5 * 4))[0];
        uint2 v6 = ((const uint2*)(z0 + (size_t)i6 * 4))[0];
        uint2 v7 = ((const uint2*)(z0 + (size_t)i7 * 4))[0];
#define ACC4(vv) { \
        a0 += bf2f((unsigned short)(vv.x & 0xFFFF)); \
        a1 += bf2f((unsigned short)(vv.x >> 16)); \
        a2 += bf2f((unsigned short)(vv.y & 0xFFFF)); \
        a3 += bf2f((unsigned short)(vv.y >> 16)); }
        ACC4(v0) ACC4(v1) ACC4(v2) ACC4(v3) ACC4(v4) ACC4(v5) ACC4(v6) ACC4(v7)
    }
    for (; k < s1; ++k) {
        uint2 v = ((const uint2*)(z0 + (size_t)csr[k] * 4))[0];
        ACC4(v)
    }
#undef ACC4
    float d = disq[n];
    a0 *= d; a1 *= d; a2 *= d; a3 *= d;
    float o[H];
#pragma unroll
    for (int h = 0; h < H; ++h)
        o[h] = fmaxf(a0 * w[0*H + h] + a1 * w[1*H + h] +
                     a2 * w[2*H + h] + a3 * w[3*H + h] + bs[h], 0.f);
    float o2[H];
#pragma unroll
    for (int h = 0; h < H; ++h) {
        float s = 0.f;
#pragma unroll
        for (int kk = 0; kk < H; ++kk) s += o[kk] * w2[kk*H + h];
        o2[h] = s * d;
    }
    unsigned pk[8];
#pragma unroll
    for (int q = 0; q < 8; ++q)
        pk[q] = (unsigned)f2bf(o2[2*q]) | ((unsigned)f2bf(o2[2*q+1]) << 16);
    uint4* yp = (uint4*)(yout + (size_t)n * H);
    yp[0] = make_uint4(pk[0], pk[1], pk[2], pk[3]);
    yp[1] = make_uint4(pk[4], pk[5], pk[6], pk[7]);
}

// ---------- conv2 gather + fused pool: h2 stays in registers/LDS, only g is written ----------
__global__ void k_gather_pool(const int* __restrict__ rs, const int* __restrict__ csr,
                              const unsigned short* __restrict__ y,
                              const float* __restrict__ b, const int* __restrict__ batch,
                              float* __restrict__ g) {
    __shared__ float red[16][H + 1];
    __shared__ int   bid[16];
    int n    = blockIdx.x * 16 + (threadIdx.x >> 4);
    int lane = threadIdx.x & 15;
    int grp  = threadIdx.x >> 4;
    float hval = 0.f;
    if (n < NN) {
        int s0 = rs[n], s1 = rs[n + 1];
        float dq = rsqrtf((float)(s1 - s0 + 1));     // bit-identical to stored disq
        float acc = bf2f(y[(size_t)n * H + lane]);   // self-loop term
        int k = s0;
        for (; k + 8 <= s1; k += 8) {
            int sa = csr[k+0], sb = csr[k+1], sc = csr[k+2], sd = csr[k+3];
            int se = csr[k+4], sf = csr[k+5], sg = csr[k+6], sh = csr[k+7];
            float v0 = bf2f(y[(size_t)sa * H + lane]);
            float v1 = bf2f(y[(size_t)sb * H + lane]);
            float v2 = bf2f(y[(size_t)sc * H + lane]);
            float v3 = bf2f(y[(size_t)sd * H + lane]);
            float v4 = bf2f(y[(size_t)se * H + lane]);
            float v5 = bf2f(y[(size_t)sf * H + lane]);
            float v6 = bf2f(y[(size_t)sg * H + lane]);
            float v7 = bf2f(y[(size_t)sh * H + lane]);
            acc += ((v0 + v1) + (v2 + v3)) + ((v4 + v5) + (v6 + v7));
        }
        for (; k < s1; ++k) acc += bf2f(y[(size_t)csr[k] * H + lane]);
        hval = fmaxf(fmaf(acc, dq, b[lane]), 0.f);
        if (lane == 0) bid[grp] = batch[n];
    } else if (lane == 0) {
        bid[grp] = -1;
    }
    red[grp][lane] = hval;
    __syncthreads();
    if (grp == 0) {
        int cur = bid[0];
        float acc = red[0][lane];
        for (int r = 1; r < 16; ++r) {
            int bb = bid[r];
            if (bb != cur) {
                if (cur >= 0) atomicAdd(&g[(size_t)cur * H + lane], acc);
                acc = 0.f;
                cur = bb;
            }
            acc += red[r][lane];
        }
        if (cur >= 0) atomicAdd(&g[(size_t)cur * H + lane], acc);
    }
}

// ---------- final MLP ----------
__global__ void k_mlp(const float* __restrict__ g, const float* __restrict__ Wf1,
                      const float* __restrict__ bf1, const float* __restrict__ Wf2,
                      const float* __restrict__ bf2, float* __restrict__ out) {
    __shared__ float w1[H * H];
    __shared__ float b1s[H];
    __shared__ float w2[H];
    __shared__ float b2s;
    if (threadIdx.x < H * H) w1[threadIdx.x] = Wf1[threadIdx.x];
    if (threadIdx.x < H) { b1s[threadIdx.x] = bf1[threadIdx.x]; w2[threadIdx.x] = Wf2[threadIdx.x]; }
    if (threadIdx.x == 0) b2s = bf2[0];
    __syncthreads();
    int i = blockIdx.x * blockDim.x + threadIdx.x;
    if (i >= NG) return;
    float gv[H];
    const float4* gp = (const float4*)(g + (size_t)i * H);
#pragma unroll
    for (int q = 0; q < 4; ++q) ((float4*)gv)[q] = gp[q];
    float s2 = 0.f;
#pragma unroll
    for (int h = 0; h < H; ++h) {
        float t = b1s[h];
#pragma unroll
        for (int k = 0; k < H; ++k) t += gv[k] * w1[k*H + h];
        s2 += fmaxf(t, 0.f) * w2[h];
    }
    out[i] = s2 + b2s;
}

// ================= fallback (baseline atomic path, f32) =================
__global__ void k_deg_init(float* __restrict__ deg) {
    int i = blockIdx.x * blockDim.x + threadIdx.x;
    if (i < NN) deg[i] = 1.0f;
}
__global__ void k_deg_edges(const int* __restrict__ dst, float* __restrict__ deg) {
    int i = blockIdx.x * blockDim.x + threadIdx.x;
    if (i < NE) atomicAdd(&deg[dst[i]], 1.0f);
}
__global__ void k_disq(float* __restrict__ deg) {
    int i = blockIdx.x * blockDim.x + threadIdx.x;
    if (i < NN) deg[i] = rsqrtf(deg[i]);
}
__global__ void k_xw1f(const float* __restrict__ x, const float* __restrict__ W1,
                       const float* __restrict__ disq, float* __restrict__ y) {
    __shared__ float w[4 * H];
    if (threadIdx.x < 4 * H) w[threadIdx.x] = W1[threadIdx.x];
    __syncthreads();
    int i = blockIdx.x * blockDim.x + threadIdx.x;
    if (i >= NN) return;
    float4 xv = ((const float4*)x)[i];
    float d = disq[i];
    float o[H];
#pragma unroll
    for (int h = 0; h < H; ++h)
        o[h] = (xv.x * w[0*H + h] + xv.y * w[1*H + h] +
                xv.z * w[2*H + h] + xv.w * w[3*H + h]) * d;
    float4* yp = (float4*)(y + (size_t)i * H);
#pragma unroll
    for (int q = 0; q < 4; ++q) yp[q] = ((float4*)o)[q];
}
__global__ void k_hw2f(const float* __restrict__ hin, const float* __restrict__ W2,
                       const float* __restrict__ disq, float* __restrict__ yout) {
    __shared__ float w[H * H];
    if (threadIdx.x < H * H) w[threadIdx.x] = W2[threadIdx.x];
    __syncthreads();
    int i = blockIdx.x * blockDim.x + threadIdx.x;
    if (i >= NN) return;
    float hv[H];
    const float4* hp = (const float4*)(hin + (size_t)i * H);
#pragma unroll
    for (int q = 0; q < 4; ++q) ((float4*)hv)[q] = hp[q];
    float d = disq[i];
    float o[H];
#pragma unroll
    for (int h = 0; h < H; ++h) {
        float s = 0.f;
#pragma unroll
        for (int k = 0; k < H; ++k) s += hv[k] * w[k*H + h];
        o[h] = s * d;
    }
    float4* yp = (float4*)(yout + (size_t)i * H);
#pragma unroll
    for (int q = 0; q < 4; ++q) yp[q] = ((float4*)o)[q];
}
__global__ void k_scatter(const int* __restrict__ src, const int* __restrict__ dst,
                          const float* __restrict__ y, float* __restrict__ acc) {
    int i = blockIdx.x * blockDim.x + threadIdx.x;
    if (i >= NE) return;
    int s = src[i], d = dst[i];
    const float4* yp = (const float4*)(y + (size_t)s * H);
    float* ap = acc + (size_t)d * H;
#pragma unroll
    for (int q = 0; q < 4; ++q) {
        float4 v = yp[q];
        atomicAdd(ap + q*4 + 0, v.x);
        atomicAdd(ap + q*4 + 1, v.y);
        atomicAdd(ap + q*4 + 2, v.z);
        atomicAdd(ap + q*4 + 3, v.w);
    }
}
__global__ void k_post(const float* __restrict__ acc, const float* __restrict__ disq,
                       const float* __restrict__ b, float* __restrict__ hout) {
    __shared__ float bs[H];
    if (threadIdx.x < H) bs[threadIdx.x] = b[threadIdx.x];
    __syncthreads();
    int i = blockIdx.x * blockDim.x + threadIdx.x;
    if (i >= NN) return;
    float d = disq[i];
    const float4* ap = (const float4*)(acc + (size_t)i * H);
    float4* hp = (float4*)(hout + (size_t)i * H);
#pragma unroll
    for (int q = 0; q < 4; ++q) {
        float4 v = ap[q];
        float4 r;
        r.x = fmaxf(v.x * d + bs[q*4+0], 0.f);
        r.y = fmaxf(v.y * d + bs[q*4+1], 0.f);
        r.z = fmaxf(v.z * d + bs[q*4+2], 0.f);
        r.w = fmaxf(v.w * d + bs[q*4+3], 0.f);
        hp[q] = r;
    }
}
__global__ void k_pool_blk(const float* __restrict__ h, const int* __restrict__ batch,
                           float* __restrict__ gout) {
    __shared__ float red[16][H + 1];
    int g    = blockIdx.x;
    int lane = threadIdx.x & 15;
    int grp  = threadIdx.x >> 4;
    int lo = 0, hi = NN;
    while (lo < hi) { int m = (lo + hi) >> 1; if (batch[m] < g) lo = m + 1; else hi = m; }
    int start = lo;
    hi = NN;
    while (lo < hi) { int m = (lo + hi) >> 1; if (batch[m] < g + 1) lo = m + 1; else hi = m; }
    int end = lo;
    float acc = 0.f;
    for (int i = start + grp; i < end; i += 16)
        acc += h[(size_t)i * H + lane];
    red[grp][lane] = acc;
    __syncthreads();
    if (grp < 8) red[grp][lane] += red[grp + 8][lane];
    __syncthreads();
    if (grp < 4) red[grp][lane] += red[grp + 4][lane];
    __syncthreads();
    if (grp < 2) red[grp][lane] += red[grp + 2][lane];
    __syncthreads();
    if (grp == 0)
        gout[(size_t)g * H + lane] = red[0][lane] + red[1][lane];
}

extern "C" void kernel_launch(void* const* d_in, const int* in_sizes, int n_in,
                              void* d_out, int out_size, void* d_ws, size_t ws_size,
                              hipStream_t stream) {
    const float* x   = (const float*)d_in[0];
    const float* W1  = (const float*)d_in[1];
    const float* b1  = (const float*)d_in[2];
    const float* W2  = (const float*)d_in[3];
    const float* b2  = (const float*)d_in[4];
    const float* Wf1 = (const float*)d_in[5];
    const float* bf1 = (const float*)d_in[6];
    const float* Wf2 = (const float*)d_in[7];
    const float* bf2 = (const float*)d_in[8];
    const int*   ei    = (const int*)d_in[9];
    const int*   batch = (const int*)d_in[10];
    const int* src = ei;        // edge_index row 0
    const int* dst = ei + NE;   // edge_index row 1
    float* out = (float*)d_out;

    const int BT  = 256;
    const int gbN = (NN + BT - 1) / BT;               // 586
    const int gbE = (NE + BT - 1) / BT;               // 18750 (fallback)
    const int NPB = BT / H;                           // 16
    const int gbG = (NN + NPB - 1) / NPB;             // 9375 gather blocks

    // ---- workspace layout (4-byte words; region starts 16B-aligned) ----
    // mat[512*512] | tot[512] | base[513]pad | ed[NE] | csr[NE] | rs[NN+1]pad |
    // disq[NN] | z0[NN*4 bf16] | ybf[NN*H bf16] | bufB slot (fallback) | g[NG*H]
    size_t need = ((size_t)14071368) * 4;   // ~56.3 MB
    if (ws_size >= need) {
        int*      mat  = (int*)d_ws;                   // 262144
        int*      tot  = mat + 262144;                 // 512
        int*      base = mat + 262656;                 // 513 (pad to 263172)
        unsigned* ed   = (unsigned*)(mat + 263172);    // NE
        int*      csr  = mat + 5063172;                // NE
        int*      rs   = mat + 9863172;                // NN+1 (pad to 10013176)
        float*    disq = (float*)(mat + 10013176);     // NN
        unsigned short* z0  = (unsigned short*)(mat + 10163176); // NN*4 bf16
        unsigned short* ybf = (unsigned short*)(mat + 10463176); // NN*H bf16
        float*    g    = (float*)(mat + 14063176);     // NG*H

        // graph bucketing (mat-driven) -> CSR + disq + z0
        k_hist2<<<NBLK, 512, 0, stream>>>(dst, mat);
        k_scanb<<<NB,   NBLK, 0, stream>>>(mat, tot);
        k_scant<<<1,    NB,  0, stream>>>(tot, base);
        k_part2<<<NBLK, 512, 0, stream>>>(src, dst, mat, tot, base, ed);
        k_csr2 <<<NB,   512, 0, stream>>>(ed, base, x, rs, csr, disq, z0);

        // conv1+hw2 fused: gather z0 (L2-resident), emit y2 bf16 directly
        k_gconv12<<<gbN, 256, 0, stream>>>(rs, csr, z0, disq, W1, b1, W2, ybf);
        // conv2 gather + fused pool (h2 never materialized)
        hipMemsetAsync(g, 0, (size_t)NG * H * sizeof(float), stream);
        k_gather_pool<<<gbG, 256, 0, stream>>>(rs, csr, ybf, b2, batch, g);
        // MLP
        k_mlp<<<1, 512, 0, stream>>>(g, Wf1, bf1, Wf2, bf2, out);
    } else {
        // fallback: baseline atomic-scatter path (~20 MB ws, f32)
        float* disq = (float*)d_ws;
        float* bufA = disq + NN;
        float* bufB = bufA + (size_t)NN * H;
        float* g    = bufB + (size_t)NN * H;

        k_deg_init<<<gbN, BT, 0, stream>>>(disq);
        k_deg_edges<<<gbE, BT, 0, stream>>>(dst, disq);
        k_disq<<<gbN, BT, 0, stream>>>(disq);

        k_xw1f<<<gbN, BT, 0, stream>>>(x, W1, disq, bufA);
        hipMemcpyAsync(bufB, bufA, (size_t)NN * H * sizeof(float),
                       hipMemcpyDeviceToDevice, stream);
        k_scatter<<<gbE, BT, 0, stream>>>(src, dst, bufA, bufB);
        k_post<<<gbN, BT, 0, stream>>>(bufB, disq, b1, bufA);

        k_hw2f<<<gbN, BT, 0, stream>>>(bufA, W2, disq, bufB);
        hipMemcpyAsync(bufA, bufB, (size_t)NN * H * sizeof(float),
                       hipMemcpyDeviceToDevice, stream);
        k_scatter<<<gbE, BT, 0, stream>>>(src, dst, bufB, bufA);
        k_post<<<gbN, BT, 0, stream>>>(bufA, disq, b2, bufB);

        k_pool_blk<<<NG, BT, 0, stream>>>(bufB, batch, g);
        k_mlp<<<1, 512, 0, stream>>>(g, Wf1, bf1, Wf2, bf2, out);
    }
}